// Round 6
// baseline (179.121 us; speedup 1.0000x reference)
//
#include <hip/hip_runtime.h>
#include <math.h>

namespace {

constexpr int Dm = 2048;

__device__ __forceinline__ float dot4(float4 u, float4 v) {
  return u.x * v.x + u.y * v.y + u.z * v.z + u.w * v.w;
}
__device__ __forceinline__ float4 add4(float4 u, float4 v) {
  return make_float4(u.x + v.x, u.y + v.y, u.z + v.z, u.w + v.w);
}

// F1: summ[m][i] = mean_s feats[m][s][i] + mod_emb[m][i]   (64 blocks)
__global__ __launch_bounds__(256) void k_summ(const float* __restrict__ feats,
                                              const float* __restrict__ mod,
                                              float* __restrict__ summ) {
  int sidx = blockIdx.x * 256 + threadIdx.x;   // 0..16383
  int m = sidx >> 11, col = sidx & 2047;
  float s = 0.f;
#pragma unroll
  for (int t = 0; t < 8; ++t) s += feats[((m * 8 + t) << 11) + col];
  summ[sidx] = s * 0.125f + mod[sidx];
}

// F2: blocks 0..511 -> h1 = relu([summ|ctx] @ rW1.T + rb1); 512..1023 -> q0 = x0 @ Wq.T + b
__global__ __launch_bounds__(256) void k_big1(const float* __restrict__ summ,
                                              const float* __restrict__ ctx,
                                              const float* __restrict__ feats,
                                              const float* __restrict__ mod,
                                              const float* __restrict__ rW1,
                                              const float* __restrict__ rb1,
                                              const float* __restrict__ W_in,
                                              const float* __restrict__ b_in,
                                              float* __restrict__ h1,
                                              float* __restrict__ q0) {
  __shared__ float As[8 * Dm];
  int tid = threadIdx.x, wave = tid >> 6, lane = tid & 63;
  if (blockIdx.x < 512) {
    for (int t = tid; t < 8 * Dm; t += 256) As[t] = summ[t];
    __syncthreads();
    int j = blockIdx.x * 4 + wave;
    const float* Wr = rW1 + (size_t)j * 4096;
    float acc[8] = {0, 0, 0, 0, 0, 0, 0, 0};
    float accC = 0.f;
    for (int i = lane * 4; i < Dm; i += 256) {
      float4 w1 = *(const float4*)(Wr + i);
      float4 w2 = *(const float4*)(Wr + 2048 + i);
      float4 c = *(const float4*)(ctx + i);
      accC += dot4(w2, c);
#pragma unroll
      for (int m = 0; m < 8; ++m) {
        float4 a = *(const float4*)(As + (m << 11) + i);
        acc[m] += dot4(w1, a);
      }
    }
#pragma unroll
    for (int o = 32; o > 0; o >>= 1) {
      accC += __shfl_down(accC, o, 64);
#pragma unroll
      for (int m = 0; m < 8; ++m) acc[m] += __shfl_down(acc[m], o, 64);
    }
    if (lane == 0) {
      float base = accC + rb1[j];
#pragma unroll
      for (int m = 0; m < 8; ++m) h1[(m << 11) + j] = fmaxf(acc[m] + base, 0.f);
    }
  } else {
    for (int t = tid; t < 8 * Dm; t += 256) {
      int m = t >> 11, col = t & 2047;
      As[t] = feats[(size_t)(m * 8) * Dm + col] + mod[(m << 11) + col];  // x[m,0,:]
    }
    __syncthreads();
    int j = (blockIdx.x - 512) * 4 + wave;
    const float* Wr = W_in + (size_t)j * Dm;
    float acc[8] = {0, 0, 0, 0, 0, 0, 0, 0};
    for (int i = lane * 4; i < Dm; i += 256) {
      float4 w = *(const float4*)(Wr + i);
#pragma unroll
      for (int m = 0; m < 8; ++m) {
        float4 a = *(const float4*)(As + (m << 11) + i);
        acc[m] += dot4(w, a);
      }
    }
#pragma unroll
    for (int o = 32; o > 0; o >>= 1)
#pragma unroll
      for (int m = 0; m < 8; ++m) acc[m] += __shfl_down(acc[m], o, 64);
    if (lane == 0) {
      float b = b_in[j];
#pragma unroll
      for (int m = 0; m < 8; ++m) q0[(m << 11) + j] = acc[m] + b;
    }
  }
}

// F3: blocks 0..255 -> h2 = relu(h1 @ rW2.T + rb2); 256..383 -> qw (per-head K projection)
__global__ __launch_bounds__(256) void k_big2(const float* __restrict__ h1,
                                              const float* __restrict__ rW2,
                                              const float* __restrict__ rb2,
                                              const float* __restrict__ q0,
                                              const float* __restrict__ W_in,
                                              float* __restrict__ h2,
                                              float* __restrict__ qw) {
  __shared__ float As[8 * Dm];
  int tid = threadIdx.x, wave = tid >> 6, lane = tid & 63;
  if (blockIdx.x < 256) {
    for (int t = tid; t < 8 * Dm; t += 256) As[t] = h1[t];
    __syncthreads();
    int j = blockIdx.x * 4 + wave;     // 0..1023
    const float* Wr = rW2 + (size_t)j * Dm;
    float acc[8] = {0, 0, 0, 0, 0, 0, 0, 0};
    for (int i = lane * 4; i < Dm; i += 256) {
      float4 w = *(const float4*)(Wr + i);
#pragma unroll
      for (int m = 0; m < 8; ++m) {
        float4 a = *(const float4*)(As + (m << 11) + i);
        acc[m] += dot4(w, a);
      }
    }
#pragma unroll
    for (int o = 32; o > 0; o >>= 1)
#pragma unroll
      for (int m = 0; m < 8; ++m) acc[m] += __shfl_down(acc[m], o, 64);
    if (lane == 0) {
      float b = rb2[j];
#pragma unroll
      for (int m = 0; m < 8; ++m) h2[m * 1024 + j] = fmaxf(acc[m] + b, 0.f);
    }
  } else {
    int bb = blockIdx.x - 256;          // 0..127
    int h = bb >> 3, chunk = bb & 7;
    int i0 = chunk * 256 + tid;
    for (int t = tid; t < 1024; t += 256) {
      int m = t >> 7, d = t & 127;
      As[t] = q0[(m << 11) + h * 128 + d];
    }
    __syncthreads();
    float acc[8] = {0, 0, 0, 0, 0, 0, 0, 0};
    const float* Wb = W_in + (size_t)(Dm + h * 128) * Dm + i0;
    for (int d = 0; d < 128; ++d) {
      float w = Wb[(size_t)d * Dm];
#pragma unroll
      for (int m = 0; m < 8; ++m) acc[m] += w * As[(m << 7) + d];
    }
#pragma unroll
    for (int m = 0; m < 8; ++m) qw[(size_t)(m * 16 + h) * Dm + i0] = acc[m];
  }
}

// F4: 128 blocks (h = bid>>3, c = bid&7): redundant route + attw(head h) + xbar[h] in LDS
//     + obar rows [h*128 + c*16, +16)
__global__ __launch_bounds__(256) void k_attn(const float* __restrict__ h2,
                                              const float* __restrict__ rW3,
                                              const float* __restrict__ rb3,
                                              const float* __restrict__ qw,
                                              const float* __restrict__ feats,
                                              const float* __restrict__ mod,
                                              const float* __restrict__ W_in,
                                              const float* __restrict__ b_in,
                                              float* __restrict__ obar,
                                              float* __restrict__ out_rw) {
  __shared__ float sig[8], wm[64], sv[64], mask_s[8], att[64];
  __shared__ float xb[Dm];
  int tid = threadIdx.x, wave = tid >> 6, lane = tid & 63;
  int h = blockIdx.x >> 3, c = blockIdx.x & 7;
  // --- routing head (redundant; ~36KB L2 reads) ---
  for (int mi = 0; mi < 2; ++mi) {
    int m = wave + mi * 4;
    float acc = 0.f;
    for (int i = lane * 4; i < 1024; i += 256) {
      float4 w = *(const float4*)(rW3 + i);
      float4 a = *(const float4*)(h2 + m * 1024 + i);
      acc += dot4(w, a);
    }
#pragma unroll
    for (int o = 32; o > 0; o >>= 1) acc += __shfl_down(acc, o, 64);
    if (lane == 0) sig[m] = 1.f / (1.f + expf(-(acc + rb3[0])));
  }
  __syncthreads();
  if (tid < 64) {
    float tot = 0.f;
#pragma unroll
    for (int m = 0; m < 8; ++m) tot += sig[m];
    int r = tid >> 3, cc = tid & 7;
    wm[tid] = (sig[r] / tot) * (sig[cc] / tot);
    if (blockIdx.x == 0 && tid < 8) out_rw[tid] = sig[tid] / tot;
  }
  __syncthreads();
  if (tid < 64) {
    float v = wm[tid];
    int rank = 0;
    for (int t = 0; t < 64; ++t) {
      float u = wm[t];
      rank += (u < v) || (u == v && t < tid);
    }
    sv[rank] = v;
  }
  __syncthreads();
  if (tid < 8) {
    double pos = 0.9 * 63.0;
    int lo = (int)pos;
    double frac = pos - (double)lo;
    float thr = (float)((double)sv[lo] + frac * ((double)sv[lo + 1] - (double)sv[lo]));
    mask_s[tid] = (wm[tid] < thr) ? -1e9f : 0.f;   // row 0 of wmat
  }
  __syncthreads();
  // --- attention weights for head h (q=0 row), x on the fly ---
  for (int mi = 0; mi < 2; ++mi) {
    int m = wave + mi * 4;
    const float* qr = qw + (size_t)(m * 16 + h) * Dm;
    float sc[8];
#pragma unroll
    for (int k = 0; k < 8; ++k) {
      const float* fr = feats + (size_t)(m * 8 + k) * Dm;
      const float* mr = mod + (size_t)m * Dm;
      float acc = 0.f;
      for (int i = lane * 4; i < Dm; i += 256) {
        float4 qv = *(const float4*)(qr + i);
        float4 xv = add4(*(const float4*)(fr + i), *(const float4*)(mr + i));
        acc += dot4(qv, xv);
      }
#pragma unroll
      for (int o = 32; o > 0; o >>= 1) acc += __shfl_xor(acc, o, 64);
      sc[k] = acc * 0.08838834764831845f + mask_s[k];
    }
    float mx = sc[0];
#pragma unroll
    for (int k = 1; k < 8; ++k) mx = fmaxf(mx, sc[k]);
    float se = 0.f;
#pragma unroll
    for (int k = 0; k < 8; ++k) { sc[k] = expf(sc[k] - mx); se += sc[k]; }
    float inv = 1.f / se;
    if (lane == 0) {
#pragma unroll
      for (int k = 0; k < 8; ++k) att[m * 8 + k] = sc[k] * inv;
    }
  }
  __syncthreads();
  // --- xbar[h] into LDS:  (sum_b att[b]*feats[b,i] + sum_m mod[m,i]) / 8 ---
  for (int i = tid; i < Dm; i += 256) {
    float acc = 0.f;
#pragma unroll
    for (int b = 0; b < 64; ++b) acc += att[b] * feats[(size_t)b * Dm + i];
    float msum = 0.f;
#pragma unroll
    for (int m = 0; m < 8; ++m) msum += mod[(size_t)m * Dm + i];
    xb[i] = (acc + msum) * 0.125f;
  }
  __syncthreads();
  // --- obar rows: 16 rows for this block (4 per wave) ---
  int row = h * 128 + c * 16 + wave * 4;
  const float* W0 = W_in + (size_t)(4096 + row) * Dm;
  float acc[4] = {0.f, 0.f, 0.f, 0.f};
  for (int i = lane * 4; i < Dm; i += 256) {
    float4 a = *(const float4*)(xb + i);
#pragma unroll
    for (int r = 0; r < 4; ++r)
      acc[r] += dot4(*(const float4*)(W0 + (size_t)r * Dm + i), a);
  }
#pragma unroll
  for (int o = 32; o > 0; o >>= 1)
#pragma unroll
    for (int r = 0; r < 4; ++r) acc[r] += __shfl_down(acc[r], o, 64);
  if (lane == 0) {
#pragma unroll
    for (int r = 0; r < 4; ++r) obar[row + r] = acc[r] + b_in[4096 + row + r];
  }
}

// generic matvec: 4 waves x RPW rows each; out[kk*OUT + j] = act(dot(A_kk, W[j]) + b[j])
template <int IN, int RPW, int ACT, bool EXPERT>
__global__ __launch_bounds__(256) void k_mv(const float* __restrict__ A, int a_stride,
                                            const float* __restrict__ Wbase, size_t wstride,
                                            const float* __restrict__ bbase, int bstride,
                                            const int* __restrict__ topi,
                                            float* __restrict__ out, int OUT) {
  __shared__ float As[IN];
  int tid = threadIdx.x, wave = tid >> 6, lane = tid & 63;
  int kk = EXPERT ? blockIdx.y : 0;
  int ei = EXPERT ? topi[kk] : 0;
  const float* Arow = A + (size_t)kk * a_stride;
  for (int t = tid; t < IN; t += 256) As[t] = Arow[t];
  __syncthreads();
  int j = blockIdx.x * (4 * RPW) + wave * RPW;
  const float* Wr = Wbase + (size_t)ei * wstride + (size_t)j * IN;
  float acc[RPW];
#pragma unroll
  for (int r = 0; r < RPW; ++r) acc[r] = 0.f;
  for (int i = lane * 4; i < IN; i += 256) {
    float4 a = *(const float4*)(As + i);
#pragma unroll
    for (int r = 0; r < RPW; ++r)
      acc[r] += dot4(*(const float4*)(Wr + (size_t)r * IN + i), a);
  }
#pragma unroll
  for (int o = 32; o > 0; o >>= 1)
#pragma unroll
    for (int r = 0; r < RPW; ++r) acc[r] += __shfl_down(acc[r], o, 64);
  if (lane == 0) {
    const float* bb = bbase + (size_t)ei * bstride;
#pragma unroll
    for (int r = 0; r < RPW; ++r) {
      float v = acc[r] + bb[j + r];
      if (ACT == 1) v = fmaxf(v, 0.f);
      if (ACT == 2) v = 0.5f * v * (1.f + erff(v * 0.70710678118654752f));
      out[(size_t)kk * OUT + j + r] = v;
    }
  }
}

// gate: logits -> softmax -> top3(stable) -> gates/topi
__global__ __launch_bounds__(512) void k_gate(const float* __restrict__ g,
                                              const float* __restrict__ gW2,
                                              const float* __restrict__ gb2,
                                              float* __restrict__ gates,
                                              int* __restrict__ topi) {
  __shared__ float logits[8];
  int wave = threadIdx.x >> 6, lane = threadIdx.x & 63;   // 512 threads
  float acc = 0.f;
  for (int i = lane * 4; i < 1024; i += 256) {
    float4 w = *(const float4*)(gW2 + wave * 1024 + i);
    float4 a = *(const float4*)(g + i);
    acc += dot4(w, a);
  }
#pragma unroll
  for (int o = 32; o > 0; o >>= 1) acc += __shfl_down(acc, o, 64);
  if (lane == 0) logits[wave] = acc + gb2[wave];
  __syncthreads();
  if (threadIdx.x == 0) {
    float mx = logits[0];
    for (int e = 1; e < 8; ++e) mx = fmaxf(mx, logits[e]);
    float p[8], se = 0.f;
    for (int e = 0; e < 8; ++e) { p[e] = expf(logits[e] - mx); se += p[e]; }
    for (int e = 0; e < 8; ++e) p[e] /= se;
    int used[8] = {0, 0, 0, 0, 0, 0, 0, 0};
    float tv[3]; int ti[3];
    for (int kk = 0; kk < 3; ++kk) {
      float bv = -1.f; int bi = -1;
      for (int e = 0; e < 8; ++e)
        if (!used[e] && p[e] > bv) { bv = p[e]; bi = e; }
      used[bi] = 1; tv[kk] = bv; ti[kk] = bi;
    }
    float m2 = tv[0];
    float s2 = 0.f, gg[3];
    for (int kk = 0; kk < 3; ++kk) { gg[kk] = expf(tv[kk] - m2); s2 += gg[kk]; }
    for (int kk = 0; kk < 3; ++kk) { gates[kk] = gg[kk] / s2; topi[kk] = ti[kk]; }
  }
}

// per-expert LayerNorm + gated combine -> fused[0:2048]
__global__ __launch_bounds__(256) void k_final(const float* __restrict__ y,
                                               const float* __restrict__ gates,
                                               const int* __restrict__ topi,
                                               const float* __restrict__ e_gamma,
                                               const float* __restrict__ e_beta,
                                               float* __restrict__ outp) {
  __shared__ float r1[256], r2[256];
  __shared__ float smu, srstd;
  int tid = threadIdx.x;
  float fused[8];
#pragma unroll
  for (int t = 0; t < 8; ++t) fused[t] = 0.f;
  for (int kk = 0; kk < 3; ++kk) {
    int ei = topi[kk];
    float gk = gates[kk];
    const float* yr = y + (size_t)kk * Dm;
    float s = 0.f, ss = 0.f;
#pragma unroll
    for (int t = 0; t < 8; ++t) {
      float v = yr[tid + 256 * t];
      s += v; ss += v * v;
    }
    r1[tid] = s; r2[tid] = ss;
    __syncthreads();
    for (int o = 128; o > 0; o >>= 1) {
      if (tid < o) { r1[tid] += r1[tid + o]; r2[tid] += r2[tid + o]; }
      __syncthreads();
    }
    if (tid == 0) {
      float mu = r1[0] * (1.f / 2048.f);
      float var = r2[0] * (1.f / 2048.f) - mu * mu;
      smu = mu;
      srstd = rsqrtf(var + 1e-5f);
    }
    __syncthreads();
    float mu = smu, rstd = srstd;
#pragma unroll
    for (int t = 0; t < 8; ++t) {
      int d = tid + 256 * t;
      float v = (yr[d] - mu) * rstd * e_gamma[(size_t)ei * Dm + d] + e_beta[(size_t)ei * Dm + d];
      fused[t] += gk * v;
    }
    __syncthreads();
  }
#pragma unroll
  for (int t = 0; t < 8; ++t) outp[tid + 256 * t] = fused[t];
}

}  // namespace

extern "C" void kernel_launch(void* const* d_in, const int* in_sizes, int n_in,
                              void* d_out, int out_size, void* d_ws, size_t ws_size,
                              hipStream_t stream) {
  const float* feats   = (const float*)d_in[0];
  const float* context = (const float*)d_in[1];
  const float* mod_emb = (const float*)d_in[2];
  const float* rW1 = (const float*)d_in[3];
  const float* rb1 = (const float*)d_in[4];
  const float* rW2 = (const float*)d_in[5];
  const float* rb2 = (const float*)d_in[6];
  const float* rW3 = (const float*)d_in[7];
  const float* rb3 = (const float*)d_in[8];
  const float* W_in  = (const float*)d_in[9];
  const float* b_in  = (const float*)d_in[10];
  const float* W_out = (const float*)d_in[11];
  const float* b_out = (const float*)d_in[12];
  const float* gW1 = (const float*)d_in[13];
  const float* gb1 = (const float*)d_in[14];
  const float* gW2 = (const float*)d_in[15];
  const float* gb2 = (const float*)d_in[16];
  const float* eW1 = (const float*)d_in[17];
  const float* eb1 = (const float*)d_in[18];
  const float* eW2 = (const float*)d_in[19];
  const float* eb2 = (const float*)d_in[20];
  const float* e_gamma = (const float*)d_in[21];
  const float* e_beta  = (const float*)d_in[22];
  float* out = (float*)d_out;
  float* ws = (float*)d_ws;

  float* summ  = ws;                 // 16384
  float* h1    = summ + 16384;       // 16384
  float* h2    = h1 + 16384;         // 8192
  float* q0    = h2 + 8192;          // 16384
  float* qw    = q0 + 16384;         // 262144
  float* obar  = qw + 262144;        // 2048
  float* attd  = obar + 2048;        // 2048
  float* gbuf  = attd + 2048;        // 1024
  float* gates = gbuf + 1024;        // 8
  int*   topi  = (int*)(gates + 8);  // 8
  float* hh    = (float*)(topi + 8); // 12288
  float* ybuf  = hh + 12288;         // 6144

  hipLaunchKernelGGL(k_summ, dim3(64), dim3(256), 0, stream, feats, mod_emb, summ);
  hipLaunchKernelGGL(k_big1, dim3(1024), dim3(256), 0, stream,
                     summ, context, feats, mod_emb, rW1, rb1, W_in, b_in, h1, q0);
  hipLaunchKernelGGL(k_big2, dim3(384), dim3(256), 0, stream,
                     h1, rW2, rb2, q0, W_in, h2, qw);
  hipLaunchKernelGGL(k_attn, dim3(128), dim3(256), 0, stream,
                     h2, rW3, rb3, qw, feats, mod_emb, W_in, b_in, obar, out + 2048);
  hipLaunchKernelGGL((k_mv<2048, 4, 0, false>), dim3(128), dim3(256), 0, stream,
                     obar, 0, W_out, 0, b_out, 0, (const int*)nullptr, attd, 2048);
  hipLaunchKernelGGL((k_mv<2048, 2, 1, false>), dim3(128), dim3(256), 0, stream,
                     attd, 0, gW1, 0, gb1, 0, (const int*)nullptr, gbuf, 1024);
  hipLaunchKernelGGL(k_gate, dim3(1), dim3(512), 0, stream, gbuf, gW2, gb2, gates, topi);
  hipLaunchKernelGGL((k_mv<2048, 4, 2, true>), dim3(256, 3), dim3(256), 0, stream,
                     attd, 0, eW1, (size_t)4096 * 2048, eb1, 4096, topi, hh, 4096);
  hipLaunchKernelGGL((k_mv<4096, 4, 0, true>), dim3(128, 3), dim3(256), 0, stream,
                     hh, 4096, eW2, (size_t)2048 * 4096, eb2, 2048, topi, ybuf, 2048);
  hipLaunchKernelGGL(k_final, dim3(1), dim3(256), 0, stream,
                     ybuf, gates, topi, e_gamma, e_beta, out);
}

// Round 7
// 133.422 us; speedup vs baseline: 1.3425x; 1.3425x over previous
//
#include <hip/hip_runtime.h>
#include <math.h>

namespace {

constexpr int Dm = 2048;

__device__ __forceinline__ float dot4(float4 u, float4 v) {
  return u.x * v.x + u.y * v.y + u.z * v.z + u.w * v.w;
}
__device__ __forceinline__ float4 add4(float4 u, float4 v) {
  return make_float4(u.x + v.x, u.y + v.y, u.z + v.z, u.w + v.w);
}

// F1: summ[m][i] = mean_s feats[m][s][i] + mod_emb[m][i]   (64 blocks)
__global__ __launch_bounds__(256) void k_summ(const float* __restrict__ feats,
                                              const float* __restrict__ mod,
                                              float* __restrict__ summ) {
  int sidx = blockIdx.x * 256 + threadIdx.x;   // 0..16383
  int m = sidx >> 11, col = sidx & 2047;
  float s = 0.f;
#pragma unroll
  for (int t = 0; t < 8; ++t) s += feats[((m * 8 + t) << 11) + col];
  summ[sidx] = s * 0.125f + mod[sidx];
}

// F2: blocks 0..511 -> h1 = relu([summ|ctx] @ rW1.T + rb1); 512..1023 -> q0 = x0 @ Wq.T + b
__global__ __launch_bounds__(256) void k_big1(const float* __restrict__ summ,
                                              const float* __restrict__ ctx,
                                              const float* __restrict__ feats,
                                              const float* __restrict__ mod,
                                              const float* __restrict__ rW1,
                                              const float* __restrict__ rb1,
                                              const float* __restrict__ W_in,
                                              const float* __restrict__ b_in,
                                              float* __restrict__ h1,
                                              float* __restrict__ q0) {
  __shared__ float As[8 * Dm];
  int tid = threadIdx.x, wave = tid >> 6, lane = tid & 63;
  if (blockIdx.x < 512) {
    for (int t = tid; t < 8 * Dm; t += 256) As[t] = summ[t];
    __syncthreads();
    int j = blockIdx.x * 4 + wave;
    const float* Wr = rW1 + (size_t)j * 4096;
    float acc[8] = {0, 0, 0, 0, 0, 0, 0, 0};
    float accC = 0.f;
    for (int i = lane * 4; i < Dm; i += 256) {
      float4 w1 = *(const float4*)(Wr + i);
      float4 w2 = *(const float4*)(Wr + 2048 + i);
      float4 c = *(const float4*)(ctx + i);
      accC += dot4(w2, c);
#pragma unroll
      for (int m = 0; m < 8; ++m) {
        float4 a = *(const float4*)(As + (m << 11) + i);
        acc[m] += dot4(w1, a);
      }
    }
#pragma unroll
    for (int o = 32; o > 0; o >>= 1) {
      accC += __shfl_down(accC, o, 64);
#pragma unroll
      for (int m = 0; m < 8; ++m) acc[m] += __shfl_down(acc[m], o, 64);
    }
    if (lane == 0) {
      float base = accC + rb1[j];
#pragma unroll
      for (int m = 0; m < 8; ++m) h1[(m << 11) + j] = fmaxf(acc[m] + base, 0.f);
    }
  } else {
    for (int t = tid; t < 8 * Dm; t += 256) {
      int m = t >> 11, col = t & 2047;
      As[t] = feats[(size_t)(m * 8) * Dm + col] + mod[(m << 11) + col];  // x[m,0,:]
    }
    __syncthreads();
    int j = (blockIdx.x - 512) * 4 + wave;
    const float* Wr = W_in + (size_t)j * Dm;
    float acc[8] = {0, 0, 0, 0, 0, 0, 0, 0};
    for (int i = lane * 4; i < Dm; i += 256) {
      float4 w = *(const float4*)(Wr + i);
#pragma unroll
      for (int m = 0; m < 8; ++m) {
        float4 a = *(const float4*)(As + (m << 11) + i);
        acc[m] += dot4(w, a);
      }
    }
#pragma unroll
    for (int o = 32; o > 0; o >>= 1)
#pragma unroll
      for (int m = 0; m < 8; ++m) acc[m] += __shfl_down(acc[m], o, 64);
    if (lane == 0) {
      float b = b_in[j];
#pragma unroll
      for (int m = 0; m < 8; ++m) q0[(m << 11) + j] = acc[m] + b;
    }
  }
}

// F3: blocks 0..255 -> h2 = relu(h1 @ rW2.T + rb2); 256..383 -> qw (per-head K projection)
__global__ __launch_bounds__(256) void k_big2(const float* __restrict__ h1,
                                              const float* __restrict__ rW2,
                                              const float* __restrict__ rb2,
                                              const float* __restrict__ q0,
                                              const float* __restrict__ W_in,
                                              float* __restrict__ h2,
                                              float* __restrict__ qw) {
  __shared__ float As[8 * Dm];
  int tid = threadIdx.x, wave = tid >> 6, lane = tid & 63;
  if (blockIdx.x < 256) {
    for (int t = tid; t < 8 * Dm; t += 256) As[t] = h1[t];
    __syncthreads();
    int j = blockIdx.x * 4 + wave;     // 0..1023
    const float* Wr = rW2 + (size_t)j * Dm;
    float acc[8] = {0, 0, 0, 0, 0, 0, 0, 0};
    for (int i = lane * 4; i < Dm; i += 256) {
      float4 w = *(const float4*)(Wr + i);
#pragma unroll
      for (int m = 0; m < 8; ++m) {
        float4 a = *(const float4*)(As + (m << 11) + i);
        acc[m] += dot4(w, a);
      }
    }
#pragma unroll
    for (int o = 32; o > 0; o >>= 1)
#pragma unroll
      for (int m = 0; m < 8; ++m) acc[m] += __shfl_down(acc[m], o, 64);
    if (lane == 0) {
      float b = rb2[j];
#pragma unroll
      for (int m = 0; m < 8; ++m) h2[m * 1024 + j] = fmaxf(acc[m] + b, 0.f);
    }
  } else {
    int bb = blockIdx.x - 256;          // 0..127
    int h = bb >> 3, chunk = bb & 7;
    int i0 = chunk * 256 + tid;
    for (int t = tid; t < 1024; t += 256) {
      int m = t >> 7, d = t & 127;
      As[t] = q0[(m << 11) + h * 128 + d];
    }
    __syncthreads();
    float acc[8] = {0, 0, 0, 0, 0, 0, 0, 0};
    const float* Wb = W_in + (size_t)(Dm + h * 128) * Dm + i0;
    for (int d = 0; d < 128; ++d) {
      float w = Wb[(size_t)d * Dm];
#pragma unroll
      for (int m = 0; m < 8; ++m) acc[m] += w * As[(m << 7) + d];
    }
#pragma unroll
    for (int m = 0; m < 8; ++m) qw[(size_t)(m * 16 + h) * Dm + i0] = acc[m];
  }
}

// F4: 16 blocks (one per head) x 512 threads (one wave per modality):
//     redundant routing head + attw(head h) + xbar[h] -> ws. No attw/xbar redundancy.
__global__ __launch_bounds__(512) void k_attn16(const float* __restrict__ h2,
                                                const float* __restrict__ rW3,
                                                const float* __restrict__ rb3,
                                                const float* __restrict__ qw,
                                                const float* __restrict__ feats,
                                                const float* __restrict__ mod,
                                                float* __restrict__ xbar,
                                                float* __restrict__ out_rw) {
  __shared__ float sig[8], wm[64], sv[64], mask_s[8], att[64];
  int tid = threadIdx.x, wave = tid >> 6, lane = tid & 63;
  int h = blockIdx.x;
  // --- routing head (redundant per block: ~36KB L2 + 8 KFLOP) ---
  {
    float acc = 0.f;
#pragma unroll
    for (int i = 0; i < 4; ++i) {
      int idx = lane * 4 + i * 256;
      float4 w = *(const float4*)(rW3 + idx);
      float4 a = *(const float4*)(h2 + wave * 1024 + idx);
      acc += dot4(w, a);
    }
#pragma unroll
    for (int o = 32; o > 0; o >>= 1) acc += __shfl_down(acc, o, 64);
    if (lane == 0) sig[wave] = 1.f / (1.f + expf(-(acc + rb3[0])));
  }
  __syncthreads();
  if (tid < 64) {
    float tot = 0.f;
#pragma unroll
    for (int m = 0; m < 8; ++m) tot += sig[m];
    int r = tid >> 3, cc = tid & 7;
    wm[tid] = (sig[r] / tot) * (sig[cc] / tot);
    if (h == 0 && tid < 8) out_rw[tid] = sig[tid] / tot;
  }
  __syncthreads();
  if (tid < 64) {
    float v = wm[tid];
    int rank = 0;
    for (int t = 0; t < 64; ++t) {
      float u = wm[t];
      rank += (u < v) || (u == v && t < tid);
    }
    sv[rank] = v;
  }
  __syncthreads();
  if (tid < 8) {
    double pos = 0.9 * 63.0;
    int lo = (int)pos;
    double frac = pos - (double)lo;
    float thr = (float)((double)sv[lo] + frac * ((double)sv[lo + 1] - (double)sv[lo]));
    mask_s[tid] = (wm[tid] < thr) ? -1e9f : 0.f;   // row 0 of wmat
  }
  __syncthreads();
  // --- attw for head h: wave = modality m, 8 k-dots of 2048, x on the fly ---
  {
    int m = wave;
    const float* qr = qw + (size_t)(m * 16 + h) * Dm;
    const float* mr = mod + (size_t)m * Dm;
    float sc[8];
#pragma unroll
    for (int k = 0; k < 8; ++k) {
      const float* fr = feats + (size_t)(m * 8 + k) * Dm;
      float acc = 0.f;
#pragma unroll
      for (int i = 0; i < 8; ++i) {
        int idx = lane * 4 + i * 256;
        float4 qv = *(const float4*)(qr + idx);
        float4 xv = add4(*(const float4*)(fr + idx), *(const float4*)(mr + idx));
        acc += dot4(qv, xv);
      }
#pragma unroll
      for (int o = 32; o > 0; o >>= 1) acc += __shfl_xor(acc, o, 64);
      sc[k] = acc * 0.08838834764831845f + mask_s[k];
    }
    float mx = sc[0];
#pragma unroll
    for (int k = 1; k < 8; ++k) mx = fmaxf(mx, sc[k]);
    float se = 0.f;
#pragma unroll
    for (int k = 0; k < 8; ++k) { sc[k] = expf(sc[k] - mx); se += sc[k]; }
    float inv = 1.f / se;
    if (lane == 0) {
#pragma unroll
      for (int k = 0; k < 8; ++k) att[m * 8 + k] = sc[k] * inv;
    }
  }
  __syncthreads();
  // --- xbar[h] -> ws: 512 threads x float4 (mod term: sum_m mod[m]/8 since sum_k att=1) ---
  {
    int i4 = tid * 4;   // 0..2044
    float4 acc = make_float4(0.f, 0.f, 0.f, 0.f);
#pragma unroll
    for (int b = 0; b < 64; ++b) {
      float a = att[b];
      float4 f = *(const float4*)(feats + (size_t)b * Dm + i4);
      acc.x += a * f.x; acc.y += a * f.y; acc.z += a * f.z; acc.w += a * f.w;
    }
#pragma unroll
    for (int m = 0; m < 8; ++m) {
      float4 f = *(const float4*)(mod + (size_t)m * Dm + i4);
      acc = add4(acc, f);
    }
    float4 r = make_float4(acc.x * 0.125f, acc.y * 0.125f, acc.z * 0.125f, acc.w * 0.125f);
    *(float4*)(xbar + (size_t)h * Dm + i4) = r;
  }
}

// 8-rows-per-block matvec (2 rows/wave): out[j] = act(dot(Arow(j/G), W[j]) + b1[j])
template <int ACT>
__global__ __launch_bounds__(256) void k_matvec8(const float* __restrict__ A, int G,
                                                 const float* __restrict__ W,
                                                 const float* __restrict__ b1,
                                                 float* __restrict__ out) {
  __shared__ float As[Dm];
  int j0 = blockIdx.x * 8;
  const float* Arow = A + (size_t)(j0 / G) * Dm;
  for (int t = threadIdx.x; t < Dm; t += 256) As[t] = Arow[t];
  __syncthreads();
  int wave = threadIdx.x >> 6, lane = threadIdx.x & 63;
  int j = j0 + wave * 2;
  const float* W0 = W + (size_t)j * Dm;
  const float* W1 = W0 + Dm;
  float acc0 = 0.f, acc1 = 0.f;
#pragma unroll 8
  for (int i = lane * 4; i < Dm; i += 256) {
    float4 a = *(const float4*)(As + i);
    float4 w0 = *(const float4*)(W0 + i);
    float4 w1 = *(const float4*)(W1 + i);
    acc0 += dot4(w0, a);
    acc1 += dot4(w1, a);
  }
#pragma unroll
  for (int o = 32; o > 0; o >>= 1) {
    acc0 += __shfl_down(acc0, o, 64);
    acc1 += __shfl_down(acc1, o, 64);
  }
  if (lane == 0) {
    float v0 = acc0 + b1[j], v1 = acc1 + b1[j + 1];
    if (ACT == 1) { v0 = fmaxf(v0, 0.f); v1 = fmaxf(v1, 0.f); }
    out[j] = v0;
    out[j + 1] = v1;
  }
}

// gate: logits -> softmax -> top3(stable) -> gates/topi in ws
__global__ __launch_bounds__(512) void k_gate(const float* __restrict__ g,
                                              const float* __restrict__ gW2,
                                              const float* __restrict__ gb2,
                                              float* __restrict__ gates,
                                              int* __restrict__ topi) {
  __shared__ float logits[8];
  int wave = threadIdx.x >> 6, lane = threadIdx.x & 63;   // 512 threads
  float acc = 0.f;
  for (int i = lane * 4; i < 1024; i += 256) {
    float4 w = *(const float4*)(gW2 + wave * 1024 + i);
    float4 a = *(const float4*)(g + i);
    acc += dot4(w, a);
  }
#pragma unroll
  for (int o = 32; o > 0; o >>= 1) acc += __shfl_down(acc, o, 64);
  if (lane == 0) logits[wave] = acc + gb2[wave];
  __syncthreads();
  if (threadIdx.x == 0) {
    float mx = logits[0];
    for (int e = 1; e < 8; ++e) mx = fmaxf(mx, logits[e]);
    float p[8], se = 0.f;
    for (int e = 0; e < 8; ++e) { p[e] = expf(logits[e] - mx); se += p[e]; }
    for (int e = 0; e < 8; ++e) p[e] /= se;
    int used[8] = {0, 0, 0, 0, 0, 0, 0, 0};
    float tv[3]; int ti[3];
    for (int kk = 0; kk < 3; ++kk) {
      float bv = -1.f; int bi = -1;
      for (int e = 0; e < 8; ++e)
        if (!used[e] && p[e] > bv) { bv = p[e]; bi = e; }
      used[bi] = 1; tv[kk] = bv; ti[kk] = bi;
    }
    float m2 = tv[0];
    float s2 = 0.f, gg[3];
    for (int kk = 0; kk < 3; ++kk) { gg[kk] = expf(tv[kk] - m2); s2 += gg[kk]; }
    for (int kk = 0; kk < 3; ++kk) { gates[kk] = gg[kk] / s2; topi[kk] = ti[kk]; }
  }
}

// expert matvec, 8 rows/block (2/wave). ACT: 0 none, 2 gelu(exact)
template <int IN, int ACT>
__global__ __launch_bounds__(256) void k_expert8(const float* __restrict__ A,
                                                 int a_stride_kk,
                                                 const float* __restrict__ Wbase,
                                                 size_t wstride,
                                                 const float* __restrict__ bbase,
                                                 int bstride,
                                                 const int* __restrict__ topi,
                                                 float* __restrict__ out, int OUT) {
  __shared__ float As[IN];
  int kk = blockIdx.y;
  int ei = topi[kk];
  const float* Arow = A + (size_t)kk * a_stride_kk;
  for (int t = threadIdx.x; t < IN; t += 256) As[t] = Arow[t];
  __syncthreads();
  int wave = threadIdx.x >> 6, lane = threadIdx.x & 63;
  int j = blockIdx.x * 8 + wave * 2;
  const float* W0 = Wbase + (size_t)ei * wstride + (size_t)j * IN;
  const float* W1 = W0 + IN;
  float acc0 = 0.f, acc1 = 0.f;
#pragma unroll 8
  for (int i = lane * 4; i < IN; i += 256) {
    float4 a = *(const float4*)(As + i);
    float4 w0 = *(const float4*)(W0 + i);
    float4 w1 = *(const float4*)(W1 + i);
    acc0 += dot4(w0, a);
    acc1 += dot4(w1, a);
  }
#pragma unroll
  for (int o = 32; o > 0; o >>= 1) {
    acc0 += __shfl_down(acc0, o, 64);
    acc1 += __shfl_down(acc1, o, 64);
  }
  if (lane == 0) {
    const float* bb = bbase + (size_t)ei * bstride;
    float v0 = acc0 + bb[j], v1 = acc1 + bb[j + 1];
    if (ACT == 2) {
      v0 = 0.5f * v0 * (1.f + erff(v0 * 0.70710678118654752f));
      v1 = 0.5f * v1 * (1.f + erff(v1 * 0.70710678118654752f));
    }
    out[(size_t)kk * OUT + j] = v0;
    out[(size_t)kk * OUT + j + 1] = v1;
  }
}

// per-expert LayerNorm + gated combine -> fused[0:2048]
__global__ __launch_bounds__(256) void k_final(const float* __restrict__ y,
                                               const float* __restrict__ gates,
                                               const int* __restrict__ topi,
                                               const float* __restrict__ e_gamma,
                                               const float* __restrict__ e_beta,
                                               float* __restrict__ outp) {
  __shared__ float r1[256], r2[256];
  __shared__ float smu, srstd;
  int tid = threadIdx.x;
  float fused[8];
#pragma unroll
  for (int t = 0; t < 8; ++t) fused[t] = 0.f;
  for (int kk = 0; kk < 3; ++kk) {
    int ei = topi[kk];
    float gk = gates[kk];
    const float* yr = y + (size_t)kk * Dm;
    float s = 0.f, ss = 0.f;
#pragma unroll
    for (int t = 0; t < 8; ++t) {
      float v = yr[tid + 256 * t];
      s += v; ss += v * v;
    }
    r1[tid] = s; r2[tid] = ss;
    __syncthreads();
    for (int o = 128; o > 0; o >>= 1) {
      if (tid < o) { r1[tid] += r1[tid + o]; r2[tid] += r2[tid + o]; }
      __syncthreads();
    }
    if (tid == 0) {
      float mu = r1[0] * (1.f / 2048.f);
      float var = r2[0] * (1.f / 2048.f) - mu * mu;
      smu = mu;
      srstd = rsqrtf(var + 1e-5f);
    }
    __syncthreads();
    float mu = smu, rstd = srstd;
#pragma unroll
    for (int t = 0; t < 8; ++t) {
      int d = tid + 256 * t;
      float v = (yr[d] - mu) * rstd * e_gamma[(size_t)ei * Dm + d] + e_beta[(size_t)ei * Dm + d];
      fused[t] += gk * v;
    }
    __syncthreads();
  }
#pragma unroll
  for (int t = 0; t < 8; ++t) outp[tid + 256 * t] = fused[t];
}

}  // namespace

extern "C" void kernel_launch(void* const* d_in, const int* in_sizes, int n_in,
                              void* d_out, int out_size, void* d_ws, size_t ws_size,
                              hipStream_t stream) {
  const float* feats   = (const float*)d_in[0];
  const float* context = (const float*)d_in[1];
  const float* mod_emb = (const float*)d_in[2];
  const float* rW1 = (const float*)d_in[3];
  const float* rb1 = (const float*)d_in[4];
  const float* rW2 = (const float*)d_in[5];
  const float* rb2 = (const float*)d_in[6];
  const float* rW3 = (const float*)d_in[7];
  const float* rb3 = (const float*)d_in[8];
  const float* W_in  = (const float*)d_in[9];
  const float* b_in  = (const float*)d_in[10];
  const float* W_out = (const float*)d_in[11];
  const float* b_out = (const float*)d_in[12];
  const float* gW1 = (const float*)d_in[13];
  const float* gb1 = (const float*)d_in[14];
  const float* gW2 = (const float*)d_in[15];
  const float* gb2 = (const float*)d_in[16];
  const float* eW1 = (const float*)d_in[17];
  const float* eb1 = (const float*)d_in[18];
  const float* eW2 = (const float*)d_in[19];
  const float* eb2 = (const float*)d_in[20];
  const float* e_gamma = (const float*)d_in[21];
  const float* e_beta  = (const float*)d_in[22];
  float* out = (float*)d_out;
  float* ws = (float*)d_ws;

  float* summ  = ws;                 // 16384
  float* h1    = summ + 16384;       // 16384
  float* h2    = h1 + 16384;         // 8192
  float* q0    = h2 + 8192;          // 16384
  float* qw    = q0 + 16384;         // 262144
  float* xbar  = qw + 262144;        // 32768
  float* obar  = xbar + 32768;       // 2048
  float* attd  = obar + 2048;        // 2048
  float* gbuf  = attd + 2048;        // 1024
  float* gates = gbuf + 1024;        // 8
  int*   topi  = (int*)(gates + 8);  // 8
  float* hh    = (float*)(topi + 8); // 12288
  float* ybuf  = hh + 12288;         // 6144

  const int BIG = 1 << 30;

  hipLaunchKernelGGL(k_summ, dim3(64), dim3(256), 0, stream, feats, mod_emb, summ);
  hipLaunchKernelGGL(k_big1, dim3(1024), dim3(256), 0, stream,
                     summ, context, feats, mod_emb, rW1, rb1, W_in, b_in, h1, q0);
  hipLaunchKernelGGL(k_big2, dim3(384), dim3(256), 0, stream,
                     h1, rW2, rb2, q0, W_in, h2, qw);
  hipLaunchKernelGGL(k_attn16, dim3(16), dim3(512), 0, stream,
                     h2, rW3, rb3, qw, feats, mod_emb, xbar, out + 2048);
  hipLaunchKernelGGL(k_matvec8<0>, dim3(256), dim3(256), 0, stream,
                     xbar, 128, W_in + (size_t)4096 * 2048, b_in + 4096, obar);
  hipLaunchKernelGGL(k_matvec8<0>, dim3(256), dim3(256), 0, stream,
                     obar, BIG, W_out, b_out, attd);
  hipLaunchKernelGGL(k_matvec8<1>, dim3(128), dim3(256), 0, stream,
                     attd, BIG, gW1, gb1, gbuf);
  hipLaunchKernelGGL(k_gate, dim3(1), dim3(512), 0, stream, gbuf, gW2, gb2, gates, topi);
  hipLaunchKernelGGL((k_expert8<2048, 2>), dim3(512, 3), dim3(256), 0, stream,
                     attd, 0, eW1, (size_t)4096 * 2048, eb1, 4096, topi, hh, 4096);
  hipLaunchKernelGGL((k_expert8<4096, 0>), dim3(256, 3), dim3(256), 0, stream,
                     hh, 4096, eW2, (size_t)2048 * 4096, eb2, 2048, topi, ybuf, 2048);
  hipLaunchKernelGGL(k_final, dim3(1), dim3(256), 0, stream,
                     ybuf, gates, topi, e_gamma, e_beta, out);
}

// Round 8
// 131.146 us; speedup vs baseline: 1.3658x; 1.0174x over previous
//
#include <hip/hip_runtime.h>
#include <math.h>

namespace {

constexpr int Dm = 2048;

__device__ __forceinline__ float dot4(float4 u, float4 v) {
  return u.x * v.x + u.y * v.y + u.z * v.z + u.w * v.w;
}
__device__ __forceinline__ float4 add4(float4 u, float4 v) {
  return make_float4(u.x + v.x, u.y + v.y, u.z + v.z, u.w + v.w);
}

// F1 (16 blocks): summ[m][i] = mean_s feats[m][s][i] + mod[m][i]  (float4)
//                 blocks 0-1 also: msum[i] = sum_m mod[m][i]
__global__ __launch_bounds__(256) void k_summ(const float* __restrict__ feats,
                                              const float* __restrict__ mod,
                                              float* __restrict__ summ,
                                              float* __restrict__ msum) {
  int t4 = blockIdx.x * 256 + threadIdx.x;   // 0..4095 float4s
  int elem = t4 * 4;
  int m = elem >> 11;
  float4 s = make_float4(0.f, 0.f, 0.f, 0.f);
#pragma unroll
  for (int t = 0; t < 8; ++t)
    s = add4(s, *(const float4*)(feats + ((size_t)(m * 8 + t) << 11) + (elem & 2047)));
  float4 md = *(const float4*)(mod + elem);
  *(float4*)(summ + elem) = make_float4(s.x * 0.125f + md.x, s.y * 0.125f + md.y,
                                        s.z * 0.125f + md.z, s.w * 0.125f + md.w);
  if (t4 < 512) {   // msum over 2048 elems
    int i4 = t4 * 4;
    float4 acc = make_float4(0.f, 0.f, 0.f, 0.f);
#pragma unroll
    for (int mm = 0; mm < 8; ++mm)
      acc = add4(acc, *(const float4*)(mod + ((size_t)mm << 11) + i4));
    *(float4*)(msum + i4) = acc;
  }
}

// F2: blocks 0..511 -> h1 = relu([summ|ctx] @ rW1.T + rb1); 512..1023 -> q0 = x0 @ Wq.T + b
__global__ __launch_bounds__(256) void k_big1(const float* __restrict__ summ,
                                              const float* __restrict__ ctx,
                                              const float* __restrict__ feats,
                                              const float* __restrict__ mod,
                                              const float* __restrict__ rW1,
                                              const float* __restrict__ rb1,
                                              const float* __restrict__ W_in,
                                              const float* __restrict__ b_in,
                                              float* __restrict__ h1,
                                              float* __restrict__ q0) {
  __shared__ float As[8 * Dm];
  int tid = threadIdx.x, wave = tid >> 6, lane = tid & 63;
  if (blockIdx.x < 512) {
    for (int t = tid; t < 8 * Dm; t += 256) As[t] = summ[t];
    __syncthreads();
    int j = blockIdx.x * 4 + wave;
    const float* Wr = rW1 + (size_t)j * 4096;
    float acc[8] = {0, 0, 0, 0, 0, 0, 0, 0};
    float accC = 0.f;
    for (int i = lane * 4; i < Dm; i += 256) {
      float4 w1 = *(const float4*)(Wr + i);
      float4 w2 = *(const float4*)(Wr + 2048 + i);
      float4 c = *(const float4*)(ctx + i);
      accC += dot4(w2, c);
#pragma unroll
      for (int m = 0; m < 8; ++m) {
        float4 a = *(const float4*)(As + (m << 11) + i);
        acc[m] += dot4(w1, a);
      }
    }
#pragma unroll
    for (int o = 32; o > 0; o >>= 1) {
      accC += __shfl_down(accC, o, 64);
#pragma unroll
      for (int m = 0; m < 8; ++m) acc[m] += __shfl_down(acc[m], o, 64);
    }
    if (lane == 0) {
      float base = accC + rb1[j];
#pragma unroll
      for (int m = 0; m < 8; ++m) h1[(m << 11) + j] = fmaxf(acc[m] + base, 0.f);
    }
  } else {
    for (int t = tid; t < 8 * Dm; t += 256) {
      int m = t >> 11, col = t & 2047;
      As[t] = feats[(size_t)(m * 8) * Dm + col] + mod[(m << 11) + col];  // x[m,0,:]
    }
    __syncthreads();
    int j = (blockIdx.x - 512) * 4 + wave;
    const float* Wr = W_in + (size_t)j * Dm;
    float acc[8] = {0, 0, 0, 0, 0, 0, 0, 0};
    for (int i = lane * 4; i < Dm; i += 256) {
      float4 w = *(const float4*)(Wr + i);
#pragma unroll
      for (int m = 0; m < 8; ++m) {
        float4 a = *(const float4*)(As + (m << 11) + i);
        acc[m] += dot4(w, a);
      }
    }
#pragma unroll
    for (int o = 32; o > 0; o >>= 1)
#pragma unroll
      for (int m = 0; m < 8; ++m) acc[m] += __shfl_down(acc[m], o, 64);
    if (lane == 0) {
      float b = b_in[j];
#pragma unroll
      for (int m = 0; m < 8; ++m) q0[(m << 11) + j] = acc[m] + b;
    }
  }
}

// F3: blocks 0..255 -> h2 = relu(h1 @ rW2.T + rb2); 256..383 -> qw (per-head K projection)
__global__ __launch_bounds__(256) void k_big2(const float* __restrict__ h1,
                                              const float* __restrict__ rW2,
                                              const float* __restrict__ rb2,
                                              const float* __restrict__ q0,
                                              const float* __restrict__ W_in,
                                              float* __restrict__ h2,
                                              float* __restrict__ qw) {
  __shared__ float As[8 * Dm];
  int tid = threadIdx.x, wave = tid >> 6, lane = tid & 63;
  if (blockIdx.x < 256) {
    for (int t = tid; t < 8 * Dm; t += 256) As[t] = h1[t];
    __syncthreads();
    int j = blockIdx.x * 4 + wave;     // 0..1023
    const float* Wr = rW2 + (size_t)j * Dm;
    float acc[8] = {0, 0, 0, 0, 0, 0, 0, 0};
    for (int i = lane * 4; i < Dm; i += 256) {
      float4 w = *(const float4*)(Wr + i);
#pragma unroll
      for (int m = 0; m < 8; ++m) {
        float4 a = *(const float4*)(As + (m << 11) + i);
        acc[m] += dot4(w, a);
      }
    }
#pragma unroll
    for (int o = 32; o > 0; o >>= 1)
#pragma unroll
      for (int m = 0; m < 8; ++m) acc[m] += __shfl_down(acc[m], o, 64);
    if (lane == 0) {
      float b = rb2[j];
#pragma unroll
      for (int m = 0; m < 8; ++m) h2[m * 1024 + j] = fmaxf(acc[m] + b, 0.f);
    }
  } else {
    int bb = blockIdx.x - 256;          // 0..127
    int h = bb >> 3, chunk = bb & 7;
    int i0 = chunk * 256 + tid;
    for (int t = tid; t < 1024; t += 256) {
      int m = t >> 7, d = t & 127;
      As[t] = q0[(m << 11) + h * 128 + d];
    }
    __syncthreads();
    float acc[8] = {0, 0, 0, 0, 0, 0, 0, 0};
    const float* Wb = W_in + (size_t)(Dm + h * 128) * Dm + i0;
    for (int d = 0; d < 128; ++d) {
      float w = Wb[(size_t)d * Dm];
#pragma unroll
      for (int m = 0; m < 8; ++m) acc[m] += w * As[(m << 7) + d];
    }
#pragma unroll
    for (int m = 0; m < 8; ++m) qw[(size_t)(m * 16 + h) * Dm + i0] = acc[m];
  }
}

// F4: 16 blocks (head h) x 512 threads (wave = modality m):
//     redundant route + attw(h) [mod term dropped: softmax shift-invariant] + xbar[h]
__global__ __launch_bounds__(512) void k_attn16(const float* __restrict__ h2,
                                                const float* __restrict__ rW3,
                                                const float* __restrict__ rb3,
                                                const float* __restrict__ qw,
                                                const float* __restrict__ feats,
                                                const float* __restrict__ msum,
                                                float* __restrict__ xbar,
                                                float* __restrict__ out_rw) {
  __shared__ float sig[8], wm[64], sv[64], mask_s[8], att[64];
  int tid = threadIdx.x, wave = tid >> 6, lane = tid & 63;
  int h = blockIdx.x;
  // --- routing head (redundant per block: ~36KB L2 + 8 KFLOP) ---
  {
    float acc = 0.f;
#pragma unroll
    for (int i = 0; i < 4; ++i) {
      int idx = lane * 4 + i * 256;
      float4 w = *(const float4*)(rW3 + idx);
      float4 a = *(const float4*)(h2 + wave * 1024 + idx);
      acc += dot4(w, a);
    }
#pragma unroll
    for (int o = 32; o > 0; o >>= 1) acc += __shfl_down(acc, o, 64);
    if (lane == 0) sig[wave] = 1.f / (1.f + expf(-(acc + rb3[0])));
  }
  __syncthreads();
  if (tid < 64) {
    float tot = 0.f;
#pragma unroll
    for (int m = 0; m < 8; ++m) tot += sig[m];
    int r = tid >> 3, cc = tid & 7;
    wm[tid] = (sig[r] / tot) * (sig[cc] / tot);
    if (h == 0 && tid < 8) out_rw[tid] = sig[tid] / tot;
  }
  __syncthreads();
  if (tid < 64) {
    float v = wm[tid];
    int rank = 0;
    for (int t = 0; t < 64; ++t) {
      float u = wm[t];
      rank += (u < v) || (u == v && t < tid);
    }
    sv[rank] = v;
  }
  __syncthreads();
  if (tid < 8) {
    double pos = 0.9 * 63.0;
    int lo = (int)pos;
    double frac = pos - (double)lo;
    float thr = (float)((double)sv[lo] + frac * ((double)sv[lo + 1] - (double)sv[lo]));
    mask_s[tid] = (wm[tid] < thr) ? -1e9f : 0.f;   // row 0 of wmat
  }
  __syncthreads();
  // --- attw for head h: wave = modality m; qr·feats only (qr·mod is k-constant) ---
  {
    int m = wave;
    const float* qr = qw + (size_t)(m * 16 + h) * Dm;
    float sc[8];
#pragma unroll
    for (int k = 0; k < 8; ++k) {
      const float* fr = feats + (size_t)(m * 8 + k) * Dm;
      float acc = 0.f;
#pragma unroll
      for (int i = 0; i < 8; ++i) {
        int idx = lane * 4 + i * 256;
        acc += dot4(*(const float4*)(qr + idx), *(const float4*)(fr + idx));
      }
#pragma unroll
      for (int o = 32; o > 0; o >>= 1) acc += __shfl_xor(acc, o, 64);
      sc[k] = acc * 0.08838834764831845f + mask_s[k];
    }
    float mx = sc[0];
#pragma unroll
    for (int k = 1; k < 8; ++k) mx = fmaxf(mx, sc[k]);
    float se = 0.f;
#pragma unroll
    for (int k = 0; k < 8; ++k) { sc[k] = expf(sc[k] - mx); se += sc[k]; }
    float inv = 1.f / se;
    if (lane == 0) {
#pragma unroll
      for (int k = 0; k < 8; ++k) att[m * 8 + k] = sc[k] * inv;
    }
  }
  __syncthreads();
  // --- xbar[h] -> ws: (sum_b att[b]*feats[b] + msum) / 8 ---
  {
    int i4 = tid * 4;   // 0..2044
    float4 acc = *(const float4*)(msum + i4);
#pragma unroll
    for (int b = 0; b < 64; ++b) {
      float a = att[b];
      float4 f = *(const float4*)(feats + (size_t)b * Dm + i4);
      acc.x += a * f.x; acc.y += a * f.y; acc.z += a * f.z; acc.w += a * f.w;
    }
    float4 r = make_float4(acc.x * 0.125f, acc.y * 0.125f, acc.z * 0.125f, acc.w * 0.125f);
    *(float4*)(xbar + (size_t)h * Dm + i4) = r;
  }
}

// 8-rows-per-block matvec (2 rows/wave), activation read direct from global (L1-cached)
template <int ACT>
__global__ __launch_bounds__(256) void k_matvec8(const float* __restrict__ A, int G,
                                                 const float* __restrict__ W,
                                                 const float* __restrict__ b1,
                                                 float* __restrict__ out) {
  int j0 = blockIdx.x * 8;
  const float* Arow = A + (size_t)(j0 / G) * Dm;
  int wave = threadIdx.x >> 6, lane = threadIdx.x & 63;
  int j = j0 + wave * 2;
  const float* W0 = W + (size_t)j * Dm;
  const float* W1 = W0 + Dm;
  float acc0 = 0.f, acc1 = 0.f;
#pragma unroll 8
  for (int i = lane * 4; i < Dm; i += 256) {
    float4 a = *(const float4*)(Arow + i);
    float4 w0 = *(const float4*)(W0 + i);
    float4 w1 = *(const float4*)(W1 + i);
    acc0 += dot4(w0, a);
    acc1 += dot4(w1, a);
  }
#pragma unroll
  for (int o = 32; o > 0; o >>= 1) {
    acc0 += __shfl_down(acc0, o, 64);
    acc1 += __shfl_down(acc1, o, 64);
  }
  if (lane == 0) {
    float v0 = acc0 + b1[j], v1 = acc1 + b1[j + 1];
    if (ACT == 1) { v0 = fmaxf(v0, 0.f); v1 = fmaxf(v1, 0.f); }
    out[j] = v0;
    out[j + 1] = v1;
  }
}

// gate: logits -> softmax -> top3(stable) -> gates/topi in ws
__global__ __launch_bounds__(512) void k_gate(const float* __restrict__ g,
                                              const float* __restrict__ gW2,
                                              const float* __restrict__ gb2,
                                              float* __restrict__ gates,
                                              int* __restrict__ topi) {
  __shared__ float logits[8];
  int wave = threadIdx.x >> 6, lane = threadIdx.x & 63;   // 512 threads
  float acc = 0.f;
  for (int i = lane * 4; i < 1024; i += 256) {
    float4 w = *(const float4*)(gW2 + wave * 1024 + i);
    float4 a = *(const float4*)(g + i);
    acc += dot4(w, a);
  }
#pragma unroll
  for (int o = 32; o > 0; o >>= 1) acc += __shfl_down(acc, o, 64);
  if (lane == 0) logits[wave] = acc + gb2[wave];
  __syncthreads();
  if (threadIdx.x == 0) {
    float mx = logits[0];
    for (int e = 1; e < 8; ++e) mx = fmaxf(mx, logits[e]);
    float p[8], se = 0.f;
    for (int e = 0; e < 8; ++e) { p[e] = expf(logits[e] - mx); se += p[e]; }
    for (int e = 0; e < 8; ++e) p[e] /= se;
    int used[8] = {0, 0, 0, 0, 0, 0, 0, 0};
    float tv[3]; int ti[3];
    for (int kk = 0; kk < 3; ++kk) {
      float bv = -1.f; int bi = -1;
      for (int e = 0; e < 8; ++e)
        if (!used[e] && p[e] > bv) { bv = p[e]; bi = e; }
      used[bi] = 1; tv[kk] = bv; ti[kk] = bi;
    }
    float m2 = tv[0];
    float s2 = 0.f, gg[3];
    for (int kk = 0; kk < 3; ++kk) { gg[kk] = expf(tv[kk] - m2); s2 += gg[kk]; }
    for (int kk = 0; kk < 3; ++kk) { gates[kk] = gg[kk] / s2; topi[kk] = ti[kk]; }
  }
}

// expert matvec, 8 rows/block (2/wave), activation direct from global. ACT: 0 none, 2 gelu
template <int IN, int ACT>
__global__ __launch_bounds__(256) void k_expert8(const float* __restrict__ A,
                                                 int a_stride_kk,
                                                 const float* __restrict__ Wbase,
                                                 size_t wstride,
                                                 const float* __restrict__ bbase,
                                                 int bstride,
                                                 const int* __restrict__ topi,
                                                 float* __restrict__ out, int OUT) {
  int kk = blockIdx.y;
  int ei = topi[kk];
  const float* Arow = A + (size_t)kk * a_stride_kk;
  int wave = threadIdx.x >> 6, lane = threadIdx.x & 63;
  int j = blockIdx.x * 8 + wave * 2;
  const float* W0 = Wbase + (size_t)ei * wstride + (size_t)j * IN;
  const float* W1 = W0 + IN;
  float acc0 = 0.f, acc1 = 0.f;
#pragma unroll 8
  for (int i = lane * 4; i < IN; i += 256) {
    float4 a = *(const float4*)(Arow + i);
    float4 w0 = *(const float4*)(W0 + i);
    float4 w1 = *(const float4*)(W1 + i);
    acc0 += dot4(w0, a);
    acc1 += dot4(w1, a);
  }
#pragma unroll
  for (int o = 32; o > 0; o >>= 1) {
    acc0 += __shfl_down(acc0, o, 64);
    acc1 += __shfl_down(acc1, o, 64);
  }
  if (lane == 0) {
    const float* bb = bbase + (size_t)ei * bstride;
    float v0 = acc0 + bb[j], v1 = acc1 + bb[j + 1];
    if (ACT == 2) {
      v0 = 0.5f * v0 * (1.f + erff(v0 * 0.70710678118654752f));
      v1 = 0.5f * v1 * (1.f + erff(v1 * 0.70710678118654752f));
    }
    out[(size_t)kk * OUT + j] = v0;
    out[(size_t)kk * OUT + j + 1] = v1;
  }
}

// per-expert LayerNorm + gated combine -> fused[0:2048]
__global__ __launch_bounds__(256) void k_final(const float* __restrict__ y,
                                               const float* __restrict__ gates,
                                               const int* __restrict__ topi,
                                               const float* __restrict__ e_gamma,
                                               const float* __restrict__ e_beta,
                                               float* __restrict__ outp) {
  __shared__ float r1[256], r2[256];
  __shared__ float smu, srstd;
  int tid = threadIdx.x;
  float fused[8];
#pragma unroll
  for (int t = 0; t < 8; ++t) fused[t] = 0.f;
  for (int kk = 0; kk < 3; ++kk) {
    int ei = topi[kk];
    float gk = gates[kk];
    const float* yr = y + (size_t)kk * Dm;
    float s = 0.f, ss = 0.f;
#pragma unroll
    for (int t = 0; t < 8; ++t) {
      float v = yr[tid + 256 * t];
      s += v; ss += v * v;
    }
    r1[tid] = s; r2[tid] = ss;
    __syncthreads();
    for (int o = 128; o > 0; o >>= 1) {
      if (tid < o) { r1[tid] += r1[tid + o]; r2[tid] += r2[tid + o]; }
      __syncthreads();
    }
    if (tid == 0) {
      float mu = r1[0] * (1.f / 2048.f);
      float var = r2[0] * (1.f / 2048.f) - mu * mu;
      smu = mu;
      srstd = rsqrtf(var + 1e-5f);
    }
    __syncthreads();
    float mu = smu, rstd = srstd;
#pragma unroll
    for (int t = 0; t < 8; ++t) {
      int d = tid + 256 * t;
      float v = (yr[d] - mu) * rstd * e_gamma[(size_t)ei * Dm + d] + e_beta[(size_t)ei * Dm + d];
      fused[t] += gk * v;
    }
    __syncthreads();
  }
#pragma unroll
  for (int t = 0; t < 8; ++t) outp[tid + 256 * t] = fused[t];
}

}  // namespace

extern "C" void kernel_launch(void* const* d_in, const int* in_sizes, int n_in,
                              void* d_out, int out_size, void* d_ws, size_t ws_size,
                              hipStream_t stream) {
  const float* feats   = (const float*)d_in[0];
  const float* context = (const float*)d_in[1];
  const float* mod_emb = (const float*)d_in[2];
  const float* rW1 = (const float*)d_in[3];
  const float* rb1 = (const float*)d_in[4];
  const float* rW2 = (const float*)d_in[5];
  const float* rb2 = (const float*)d_in[6];
  const float* rW3 = (const float*)d_in[7];
  const float* rb3 = (const float*)d_in[8];
  const float* W_in  = (const float*)d_in[9];
  const float* b_in  = (const float*)d_in[10];
  const float* W_out = (const float*)d_in[11];
  const float* b_out = (const float*)d_in[12];
  const float* gW1 = (const float*)d_in[13];
  const float* gb1 = (const float*)d_in[14];
  const float* gW2 = (const float*)d_in[15];
  const float* gb2 = (const float*)d_in[16];
  const float* eW1 = (const float*)d_in[17];
  const float* eb1 = (const float*)d_in[18];
  const float* eW2 = (const float*)d_in[19];
  const float* eb2 = (const float*)d_in[20];
  const float* e_gamma = (const float*)d_in[21];
  const float* e_beta  = (const float*)d_in[22];
  float* out = (float*)d_out;
  float* ws = (float*)d_ws;

  float* summ  = ws;                 // 16384
  float* msum  = summ + 16384;       // 2048
  float* h1    = msum + 2048;        // 16384
  float* h2    = h1 + 16384;         // 8192
  float* q0    = h2 + 8192;          // 16384
  float* qw    = q0 + 16384;         // 262144
  float* xbar  = qw + 262144;        // 32768
  float* obar  = xbar + 32768;       // 2048
  float* attd  = obar + 2048;        // 2048
  float* gbuf  = attd + 2048;        // 1024
  float* gates = gbuf + 1024;        // 8
  int*   topi  = (int*)(gates + 8);  // 8
  float* hh    = (float*)(topi + 8); // 12288
  float* ybuf  = hh + 12288;         // 6144

  const int BIG = 1 << 30;

  hipLaunchKernelGGL(k_summ, dim3(16), dim3(256), 0, stream, feats, mod_emb, summ, msum);
  hipLaunchKernelGGL(k_big1, dim3(1024), dim3(256), 0, stream,
                     summ, context, feats, mod_emb, rW1, rb1, W_in, b_in, h1, q0);
  hipLaunchKernelGGL(k_big2, dim3(384), dim3(256), 0, stream,
                     h1, rW2, rb2, q0, W_in, h2, qw);
  hipLaunchKernelGGL(k_attn16, dim3(16), dim3(512), 0, stream,
                     h2, rW3, rb3, qw, feats, msum, xbar, out + 2048);
  hipLaunchKernelGGL(k_matvec8<0>, dim3(256), dim3(256), 0, stream,
                     xbar, 128, W_in + (size_t)4096 * 2048, b_in + 4096, obar);
  hipLaunchKernelGGL(k_matvec8<0>, dim3(256), dim3(256), 0, stream,
                     obar, BIG, W_out, b_out, attd);
  hipLaunchKernelGGL(k_matvec8<1>, dim3(128), dim3(256), 0, stream,
                     attd, BIG, gW1, gb1, gbuf);
  hipLaunchKernelGGL(k_gate, dim3(1), dim3(512), 0, stream, gbuf, gW2, gb2, gates, topi);
  hipLaunchKernelGGL((k_expert8<2048, 2>), dim3(512, 3), dim3(256), 0, stream,
                     attd, 0, eW1, (size_t)4096 * 2048, eb1, 4096, topi, hh, 4096);
  hipLaunchKernelGGL((k_expert8<4096, 0>), dim3(256, 3), dim3(256), 0, stream,
                     hh, 4096, eW2, (size_t)2048 * 4096, eb2, 2048, topi, ybuf, 2048);
  hipLaunchKernelGGL(k_final, dim3(1), dim3(256), 0, stream,
                     ybuf, gates, topi, e_gamma, e_beta, out);
}

// Round 9
// 130.186 us; speedup vs baseline: 1.3759x; 1.0074x over previous
//
#include <hip/hip_runtime.h>
#include <math.h>

namespace {

constexpr int Dm = 2048;

__device__ __forceinline__ float dot4(float4 u, float4 v) {
  return u.x * v.x + u.y * v.y + u.z * v.z + u.w * v.w;
}
__device__ __forceinline__ float4 add4(float4 u, float4 v) {
  return make_float4(u.x + v.x, u.y + v.y, u.z + v.z, u.w + v.w);
}

// top-3 expert indices from logits (strict >, lower index wins ties — matches lax.top_k)
__device__ __forceinline__ void top3_from_logits(const float* l, int* ti) {
  int used0 = -1, used1 = -1;
  for (int kk = 0; kk < 3; ++kk) {
    float bv = -1e30f; int bi = -1;
#pragma unroll
    for (int e = 0; e < 8; ++e) {
      if (e == used0 || e == used1) continue;
      if (l[e] > bv) { bv = l[e]; bi = e; }
    }
    ti[kk] = bi;
    if (kk == 0) used0 = bi; else if (kk == 1) used1 = bi;
  }
}

// F1 (16 blocks): summ = mean_s feats + mod (float4); blocks 0-1: msum; block 0: zero logits
__global__ __launch_bounds__(256) void k_summ(const float* __restrict__ feats,
                                              const float* __restrict__ mod,
                                              float* __restrict__ summ,
                                              float* __restrict__ msum,
                                              float* __restrict__ logits) {
  int t4 = blockIdx.x * 256 + threadIdx.x;   // 0..4095 float4s
  int elem = t4 * 4;
  int m = elem >> 11;
  float4 s = make_float4(0.f, 0.f, 0.f, 0.f);
#pragma unroll
  for (int t = 0; t < 8; ++t)
    s = add4(s, *(const float4*)(feats + ((size_t)(m * 8 + t) << 11) + (elem & 2047)));
  float4 md = *(const float4*)(mod + elem);
  *(float4*)(summ + elem) = make_float4(s.x * 0.125f + md.x, s.y * 0.125f + md.y,
                                        s.z * 0.125f + md.z, s.w * 0.125f + md.w);
  if (t4 < 512) {   // msum over 2048 elems
    int i4 = t4 * 4;
    float4 acc = make_float4(0.f, 0.f, 0.f, 0.f);
#pragma unroll
    for (int mm = 0; mm < 8; ++mm)
      acc = add4(acc, *(const float4*)(mod + ((size_t)mm << 11) + i4));
    *(float4*)(msum + i4) = acc;
  }
  if (blockIdx.x == 0 && threadIdx.x < 8) logits[threadIdx.x] = 0.f;
}

// F2: blocks 0..511 -> h1 = relu([summ|ctx] @ rW1.T + rb1); 512..1023 -> q0 = x0 @ Wq.T + b
__global__ __launch_bounds__(256) void k_big1(const float* __restrict__ summ,
                                              const float* __restrict__ ctx,
                                              const float* __restrict__ feats,
                                              const float* __restrict__ mod,
                                              const float* __restrict__ rW1,
                                              const float* __restrict__ rb1,
                                              const float* __restrict__ W_in,
                                              const float* __restrict__ b_in,
                                              float* __restrict__ h1,
                                              float* __restrict__ q0) {
  __shared__ float As[8 * Dm];
  int tid = threadIdx.x, wave = tid >> 6, lane = tid & 63;
  if (blockIdx.x < 512) {
    for (int t = tid; t < 8 * Dm; t += 256) As[t] = summ[t];
    __syncthreads();
    int j = blockIdx.x * 4 + wave;
    const float* Wr = rW1 + (size_t)j * 4096;
    float acc[8] = {0, 0, 0, 0, 0, 0, 0, 0};
    float accC = 0.f;
    for (int i = lane * 4; i < Dm; i += 256) {
      float4 w1 = *(const float4*)(Wr + i);
      float4 w2 = *(const float4*)(Wr + 2048 + i);
      float4 c = *(const float4*)(ctx + i);
      accC += dot4(w2, c);
#pragma unroll
      for (int m = 0; m < 8; ++m) {
        float4 a = *(const float4*)(As + (m << 11) + i);
        acc[m] += dot4(w1, a);
      }
    }
#pragma unroll
    for (int o = 32; o > 0; o >>= 1) {
      accC += __shfl_down(accC, o, 64);
#pragma unroll
      for (int m = 0; m < 8; ++m) acc[m] += __shfl_down(acc[m], o, 64);
    }
    if (lane == 0) {
      float base = accC + rb1[j];
#pragma unroll
      for (int m = 0; m < 8; ++m) h1[(m << 11) + j] = fmaxf(acc[m] + base, 0.f);
    }
  } else {
    for (int t = tid; t < 8 * Dm; t += 256) {
      int m = t >> 11, col = t & 2047;
      As[t] = feats[(size_t)(m * 8) * Dm + col] + mod[(m << 11) + col];  // x[m,0,:]
    }
    __syncthreads();
    int j = (blockIdx.x - 512) * 4 + wave;
    const float* Wr = W_in + (size_t)j * Dm;
    float acc[8] = {0, 0, 0, 0, 0, 0, 0, 0};
    for (int i = lane * 4; i < Dm; i += 256) {
      float4 w = *(const float4*)(Wr + i);
#pragma unroll
      for (int m = 0; m < 8; ++m) {
        float4 a = *(const float4*)(As + (m << 11) + i);
        acc[m] += dot4(w, a);
      }
    }
#pragma unroll
    for (int o = 32; o > 0; o >>= 1)
#pragma unroll
      for (int m = 0; m < 8; ++m) acc[m] += __shfl_down(acc[m], o, 64);
    if (lane == 0) {
      float b = b_in[j];
#pragma unroll
      for (int m = 0; m < 8; ++m) q0[(m << 11) + j] = acc[m] + b;
    }
  }
}

// F3: blocks 0..255 -> h2 = relu(h1 @ rW2.T + rb2); 256..383 -> qw (per-head K projection)
__global__ __launch_bounds__(256) void k_big2(const float* __restrict__ h1,
                                              const float* __restrict__ rW2,
                                              const float* __restrict__ rb2,
                                              const float* __restrict__ q0,
                                              const float* __restrict__ W_in,
                                              float* __restrict__ h2,
                                              float* __restrict__ qw) {
  __shared__ float As[8 * Dm];
  int tid = threadIdx.x, wave = tid >> 6, lane = tid & 63;
  if (blockIdx.x < 256) {
    for (int t = tid; t < 8 * Dm; t += 256) As[t] = h1[t];
    __syncthreads();
    int j = blockIdx.x * 4 + wave;     // 0..1023
    const float* Wr = rW2 + (size_t)j * Dm;
    float acc[8] = {0, 0, 0, 0, 0, 0, 0, 0};
    for (int i = lane * 4; i < Dm; i += 256) {
      float4 w = *(const float4*)(Wr + i);
#pragma unroll
      for (int m = 0; m < 8; ++m) {
        float4 a = *(const float4*)(As + (m << 11) + i);
        acc[m] += dot4(w, a);
      }
    }
#pragma unroll
    for (int o = 32; o > 0; o >>= 1)
#pragma unroll
      for (int m = 0; m < 8; ++m) acc[m] += __shfl_down(acc[m], o, 64);
    if (lane == 0) {
      float b = rb2[j];
#pragma unroll
      for (int m = 0; m < 8; ++m) h2[m * 1024 + j] = fmaxf(acc[m] + b, 0.f);
    }
  } else {
    int bb = blockIdx.x - 256;          // 0..127
    int h = bb >> 3, chunk = bb & 7;
    int i0 = chunk * 256 + tid;
    for (int t = tid; t < 1024; t += 256) {
      int m = t >> 7, d = t & 127;
      As[t] = q0[(m << 11) + h * 128 + d];
    }
    __syncthreads();
    float acc[8] = {0, 0, 0, 0, 0, 0, 0, 0};
    const float* Wb = W_in + (size_t)(Dm + h * 128) * Dm + i0;
    for (int d = 0; d < 128; ++d) {
      float w = Wb[(size_t)d * Dm];
#pragma unroll
      for (int m = 0; m < 8; ++m) acc[m] += w * As[(m << 7) + d];
    }
#pragma unroll
    for (int m = 0; m < 8; ++m) qw[(size_t)(m * 16 + h) * Dm + i0] = acc[m];
  }
}

// F4: 32 blocks x 256 thr (wave = one mh pair): redundant route + attw -> att[128][8]
__global__ __launch_bounds__(256) void k_attnw(const float* __restrict__ h2,
                                               const float* __restrict__ rW3,
                                               const float* __restrict__ rb3,
                                               const float* __restrict__ qw,
                                               const float* __restrict__ feats,
                                               float* __restrict__ att,
                                               float* __restrict__ out_rw) {
  __shared__ float sig[8], wm[64], sv[64], mask_s[8];
  int tid = threadIdx.x, wave = tid >> 6, lane = tid & 63;
  // --- routing head (redundant per block: ~36KB L2 + 8 KFLOP) ---
  for (int mi = 0; mi < 2; ++mi) {
    int m = wave + mi * 4;
    float acc = 0.f;
    for (int i = lane * 4; i < 1024; i += 256) {
      float4 w = *(const float4*)(rW3 + i);
      float4 a = *(const float4*)(h2 + m * 1024 + i);
      acc += dot4(w, a);
    }
#pragma unroll
    for (int o = 32; o > 0; o >>= 1) acc += __shfl_down(acc, o, 64);
    if (lane == 0) sig[m] = 1.f / (1.f + expf(-(acc + rb3[0])));
  }
  __syncthreads();
  if (tid < 64) {
    float tot = 0.f;
#pragma unroll
    for (int m = 0; m < 8; ++m) tot += sig[m];
    int r = tid >> 3, cc = tid & 7;
    wm[tid] = (sig[r] / tot) * (sig[cc] / tot);
    if (blockIdx.x == 0 && tid < 8) out_rw[tid] = sig[tid] / tot;
  }
  __syncthreads();
  if (tid < 64) {
    float v = wm[tid];
    int rank = 0;
    for (int t = 0; t < 64; ++t) {
      float u = wm[t];
      rank += (u < v) || (u == v && t < tid);
    }
    sv[rank] = v;
  }
  __syncthreads();
  if (tid < 8) {
    double pos = 0.9 * 63.0;
    int lo = (int)pos;
    double frac = pos - (double)lo;
    float thr = (float)((double)sv[lo] + frac * ((double)sv[lo + 1] - (double)sv[lo]));
    mask_s[tid] = (wm[tid] < thr) ? -1e9f : 0.f;   // row 0 of wmat
  }
  __syncthreads();
  // --- attw: wave = mh = bid*4+wave; qr·feats only (mod term is k-constant, softmax-invariant)
  {
    int mh = blockIdx.x * 4 + wave;   // 0..127
    int m = mh >> 4;
    const float* qr = qw + (size_t)mh * Dm;
    float sc[8];
#pragma unroll
    for (int k = 0; k < 8; ++k) {
      const float* fr = feats + (size_t)(m * 8 + k) * Dm;
      float acc = 0.f;
#pragma unroll
      for (int i = 0; i < 8; ++i) {
        int idx = lane * 4 + i * 256;
        acc += dot4(*(const float4*)(qr + idx), *(const float4*)(fr + idx));
      }
#pragma unroll
      for (int o = 32; o > 0; o >>= 1) acc += __shfl_xor(acc, o, 64);
      sc[k] = acc * 0.08838834764831845f + mask_s[k];
    }
    float mx = sc[0];
#pragma unroll
    for (int k = 1; k < 8; ++k) mx = fmaxf(mx, sc[k]);
    float se = 0.f;
#pragma unroll
    for (int k = 0; k < 8; ++k) { sc[k] = expf(sc[k] - mx); se += sc[k]; }
    float inv = 1.f / se;
    if (lane == 0) {
#pragma unroll
      for (int k = 0; k < 8; ++k) att[mh * 8 + k] = sc[k] * inv;
    }
  }
}

// F5: grid (8,16): xbar[h][i-chunk] = (sum_b att*feats + msum)/8
__global__ __launch_bounds__(256) void k_xbar(const float* __restrict__ att,
                                              const float* __restrict__ feats,
                                              const float* __restrict__ msum,
                                              float* __restrict__ xbar) {
  __shared__ float aw[64];
  int h = blockIdx.y;
  int i = blockIdx.x * 256 + threadIdx.x;
  if (threadIdx.x < 64) {
    int m = threadIdx.x >> 3, k = threadIdx.x & 7;
    aw[threadIdx.x] = att[(m * 16 + h) * 8 + k];
  }
  __syncthreads();
  float acc = msum[i];
#pragma unroll
  for (int b = 0; b < 64; ++b) acc += aw[b] * feats[(size_t)b * Dm + i];
  xbar[(size_t)h * Dm + i] = acc * 0.125f;
}

// 8-rows-per-block matvec (2 rows/wave), activation direct from global (L1/L2-cached)
template <int ACT>
__global__ __launch_bounds__(256) void k_matvec8(const float* __restrict__ A, int G,
                                                 const float* __restrict__ W,
                                                 const float* __restrict__ b1,
                                                 float* __restrict__ out) {
  int j0 = blockIdx.x * 8;
  const float* Arow = A + (size_t)(j0 / G) * Dm;
  int wave = threadIdx.x >> 6, lane = threadIdx.x & 63;
  int j = j0 + wave * 2;
  const float* W0 = W + (size_t)j * Dm;
  const float* W1 = W0 + Dm;
  float acc0 = 0.f, acc1 = 0.f;
#pragma unroll 8
  for (int i = lane * 4; i < Dm; i += 256) {
    float4 a = *(const float4*)(Arow + i);
    float4 w0 = *(const float4*)(W0 + i);
    float4 w1 = *(const float4*)(W1 + i);
    acc0 += dot4(w0, a);
    acc1 += dot4(w1, a);
  }
#pragma unroll
  for (int o = 32; o > 0; o >>= 1) {
    acc0 += __shfl_down(acc0, o, 64);
    acc1 += __shfl_down(acc1, o, 64);
  }
  if (lane == 0) {
    float v0 = acc0 + b1[j], v1 = acc1 + b1[j + 1];
    if (ACT == 1) { v0 = fmaxf(v0, 0.f); v1 = fmaxf(v1, 0.f); }
    out[j] = v0;
    out[j + 1] = v1;
  }
}

// F8: 128 blocks: gbuf rows (in-register) + per-block partial gate logits via atomicAdd
__global__ __launch_bounds__(256) void k_gbufL(const float* __restrict__ attd,
                                               const float* __restrict__ gW1,
                                               const float* __restrict__ gb1,
                                               const float* __restrict__ gW2,
                                               float* __restrict__ logits) {
  __shared__ float gv[8];
  int tid = threadIdx.x, wave = tid >> 6, lane = tid & 63;
  int j0 = blockIdx.x * 8;
  int j = j0 + wave * 2;
  const float* W0 = gW1 + (size_t)j * Dm;
  const float* W1 = W0 + Dm;
  float acc0 = 0.f, acc1 = 0.f;
#pragma unroll 8
  for (int i = lane * 4; i < Dm; i += 256) {
    float4 a = *(const float4*)(attd + i);
    float4 w0 = *(const float4*)(W0 + i);
    float4 w1 = *(const float4*)(W1 + i);
    acc0 += dot4(w0, a);
    acc1 += dot4(w1, a);
  }
#pragma unroll
  for (int o = 32; o > 0; o >>= 1) {
    acc0 += __shfl_down(acc0, o, 64);
    acc1 += __shfl_down(acc1, o, 64);
  }
  if (lane == 0) {
    gv[wave * 2] = fmaxf(acc0 + gb1[j], 0.f);
    gv[wave * 2 + 1] = fmaxf(acc1 + gb1[j + 1], 0.f);
  }
  __syncthreads();
  if (tid < 8) {
    float pl = 0.f;
#pragma unroll
    for (int r = 0; r < 8; ++r) pl += gW2[tid * 1024 + j0 + r] * gv[r];
    atomicAdd(&logits[tid], pl);
  }
}

// expert matvec, 8 rows/block (2/wave); expert index from in-register top-3 of logits
template <int IN, int ACT>
__global__ __launch_bounds__(256) void k_expert8(const float* __restrict__ A,
                                                 int a_stride_kk,
                                                 const float* __restrict__ Wbase,
                                                 size_t wstride,
                                                 const float* __restrict__ bbase,
                                                 int bstride,
                                                 const float* __restrict__ logits,
                                                 const float* __restrict__ gb2,
                                                 float* __restrict__ out, int OUT) {
  int kk = blockIdx.y;
  float l[8];
#pragma unroll
  for (int e = 0; e < 8; ++e) l[e] = logits[e] + gb2[e];
  int ti[3];
  top3_from_logits(l, ti);
  int ei = ti[kk];
  const float* Arow = A + (size_t)kk * a_stride_kk;
  int wave = threadIdx.x >> 6, lane = threadIdx.x & 63;
  int j = blockIdx.x * 8 + wave * 2;
  const float* W0 = Wbase + (size_t)ei * wstride + (size_t)j * IN;
  const float* W1 = W0 + IN;
  float acc0 = 0.f, acc1 = 0.f;
#pragma unroll 8
  for (int i = lane * 4; i < IN; i += 256) {
    float4 a = *(const float4*)(Arow + i);
    float4 w0 = *(const float4*)(W0 + i);
    float4 w1 = *(const float4*)(W1 + i);
    acc0 += dot4(w0, a);
    acc1 += dot4(w1, a);
  }
#pragma unroll
  for (int o = 32; o > 0; o >>= 1) {
    acc0 += __shfl_down(acc0, o, 64);
    acc1 += __shfl_down(acc1, o, 64);
  }
  if (lane == 0) {
    const float* bb = bbase + (size_t)ei * bstride;
    float v0 = acc0 + bb[j], v1 = acc1 + bb[j + 1];
    if (ACT == 2) {
      v0 = 0.5f * v0 * (1.f + erff(v0 * 0.70710678118654752f));
      v1 = 0.5f * v1 * (1.f + erff(v1 * 0.70710678118654752f));
    }
    out[(size_t)kk * OUT + j] = v0;
    out[(size_t)kk * OUT + j + 1] = v1;
  }
}

// F11: per-expert LayerNorm + gated combine (gate recomputed in-register from logits)
__global__ __launch_bounds__(256) void k_final(const float* __restrict__ y,
                                               const float* __restrict__ logits,
                                               const float* __restrict__ gb2,
                                               const float* __restrict__ e_gamma,
                                               const float* __restrict__ e_beta,
                                               float* __restrict__ outp) {
  __shared__ float ws_s[4], ws_ss[4];
  int tid = threadIdx.x, wave = tid >> 6, lane = tid & 63;
  float l[8];
#pragma unroll
  for (int e = 0; e < 8; ++e) l[e] = logits[e] + gb2[e];
  int ti[3];
  top3_from_logits(l, ti);
  float mx = l[0];
#pragma unroll
  for (int e = 1; e < 8; ++e) mx = fmaxf(mx, l[e]);
  float se = 0.f;
  float p[8];
#pragma unroll
  for (int e = 0; e < 8; ++e) { p[e] = expf(l[e] - mx); se += p[e]; }
  float tv0 = p[ti[0]] / se, tv1 = p[ti[1]] / se, tv2 = p[ti[2]] / se;
  float g0 = 1.f, g1 = expf(tv1 - tv0), g2 = expf(tv2 - tv0);
  float gs = g0 + g1 + g2;
  float gates[3] = {g0 / gs, g1 / gs, g2 / gs};
  float fused[8];
#pragma unroll
  for (int t = 0; t < 8; ++t) fused[t] = 0.f;
  for (int kk = 0; kk < 3; ++kk) {
    int ei = ti[kk];
    float gk = gates[kk];
    const float* yr = y + (size_t)kk * Dm;
    float s = 0.f, ss = 0.f;
    float vbuf[8];
#pragma unroll
    for (int t = 0; t < 8; ++t) {
      float v = yr[tid + 256 * t];
      vbuf[t] = v;
      s += v; ss += v * v;
    }
#pragma unroll
    for (int o = 32; o > 0; o >>= 1) {
      s += __shfl_down(s, o, 64);
      ss += __shfl_down(ss, o, 64);
    }
    if (lane == 0) { ws_s[wave] = s; ws_ss[wave] = ss; }
    __syncthreads();
    float S = ws_s[0] + ws_s[1] + ws_s[2] + ws_s[3];
    float SS = ws_ss[0] + ws_ss[1] + ws_ss[2] + ws_ss[3];
    float mu = S * (1.f / 2048.f);
    float var = SS * (1.f / 2048.f) - mu * mu;
    float rstd = rsqrtf(var + 1e-5f);
#pragma unroll
    for (int t = 0; t < 8; ++t) {
      int d = tid + 256 * t;
      fused[t] += gk * ((vbuf[t] - mu) * rstd * e_gamma[(size_t)ei * Dm + d] +
                        e_beta[(size_t)ei * Dm + d]);
    }
    __syncthreads();
  }
#pragma unroll
  for (int t = 0; t < 8; ++t) outp[tid + 256 * t] = fused[t];
}

}  // namespace

extern "C" void kernel_launch(void* const* d_in, const int* in_sizes, int n_in,
                              void* d_out, int out_size, void* d_ws, size_t ws_size,
                              hipStream_t stream) {
  const float* feats   = (const float*)d_in[0];
  const float* context = (const float*)d_in[1];
  const float* mod_emb = (const float*)d_in[2];
  const float* rW1 = (const float*)d_in[3];
  const float* rb1 = (const float*)d_in[4];
  const float* rW2 = (const float*)d_in[5];
  const float* rb2 = (const float*)d_in[6];
  const float* rW3 = (const float*)d_in[7];
  const float* rb3 = (const float*)d_in[8];
  const float* W_in  = (const float*)d_in[9];
  const float* b_in  = (const float*)d_in[10];
  const float* W_out = (const float*)d_in[11];
  const float* b_out = (const float*)d_in[12];
  const float* gW1 = (const float*)d_in[13];
  const float* gb1 = (const float*)d_in[14];
  const float* gW2 = (const float*)d_in[15];
  const float* gb2 = (const float*)d_in[16];
  const float* eW1 = (const float*)d_in[17];
  const float* eb1 = (const float*)d_in[18];
  const float* eW2 = (const float*)d_in[19];
  const float* eb2 = (const float*)d_in[20];
  const float* e_gamma = (const float*)d_in[21];
  const float* e_beta  = (const float*)d_in[22];
  float* out = (float*)d_out;
  float* ws = (float*)d_ws;

  float* summ   = ws;                  // 16384
  float* msum   = summ + 16384;        // 2048
  float* h1     = msum + 2048;         // 16384
  float* h2     = h1 + 16384;          // 8192
  float* q0     = h2 + 8192;           // 16384
  float* qw     = q0 + 16384;          // 262144
  float* att    = qw + 262144;         // 1024
  float* xbar   = att + 1024;          // 32768
  float* obar   = xbar + 32768;        // 2048
  float* attd   = obar + 2048;         // 2048
  float* logits = attd + 2048;         // 8
  float* hh     = logits + 8;          // 12288
  float* ybuf   = hh + 12288;          // 6144

  const int BIG = 1 << 30;

  hipLaunchKernelGGL(k_summ, dim3(16), dim3(256), 0, stream,
                     feats, mod_emb, summ, msum, logits);
  hipLaunchKernelGGL(k_big1, dim3(1024), dim3(256), 0, stream,
                     summ, context, feats, mod_emb, rW1, rb1, W_in, b_in, h1, q0);
  hipLaunchKernelGGL(k_big2, dim3(384), dim3(256), 0, stream,
                     h1, rW2, rb2, q0, W_in, h2, qw);
  hipLaunchKernelGGL(k_attnw, dim3(32), dim3(256), 0, stream,
                     h2, rW3, rb3, qw, feats, att, out + 2048);
  hipLaunchKernelGGL(k_xbar, dim3(8, 16), dim3(256), 0, stream, att, feats, msum, xbar);
  hipLaunchKernelGGL(k_matvec8<0>, dim3(256), dim3(256), 0, stream,
                     xbar, 128, W_in + (size_t)4096 * 2048, b_in + 4096, obar);
  hipLaunchKernelGGL(k_matvec8<0>, dim3(256), dim3(256), 0, stream,
                     obar, BIG, W_out, b_out, attd);
  hipLaunchKernelGGL(k_gbufL, dim3(128), dim3(256), 0, stream,
                     attd, gW1, gb1, gW2, logits);
  hipLaunchKernelGGL((k_expert8<2048, 2>), dim3(512, 3), dim3(256), 0, stream,
                     attd, 0, eW1, (size_t)4096 * 2048, eb1, 4096, logits, gb2, hh, 4096);
  hipLaunchKernelGGL((k_expert8<4096, 0>), dim3(256, 3), dim3(256), 0, stream,
                     hh, 4096, eW2, (size_t)2048 * 4096, eb2, 2048, logits, gb2, ybuf, 2048);
  hipLaunchKernelGGL(k_final, dim3(1), dim3(256), 0, stream,
                     ybuf, logits, gb2, e_gamma, e_beta, out);
}

// Round 10
// 116.866 us; speedup vs baseline: 1.5327x; 1.1140x over previous
//
#include <hip/hip_runtime.h>
#include <math.h>

namespace {

constexpr int Dm = 2048;

using f4n = __attribute__((ext_vector_type(4))) float;

__device__ __forceinline__ float dot4(float4 u, float4 v) {
  return u.x * v.x + u.y * v.y + u.z * v.z + u.w * v.w;
}
__device__ __forceinline__ float4 add4(float4 u, float4 v) {
  return make_float4(u.x + v.x, u.y + v.y, u.z + v.z, u.w + v.w);
}
// non-temporal weight dot (evict-first: keeps L3 for reused weights)
__device__ __forceinline__ float dot4nt(const float* p, float4 a) {
  f4n w = __builtin_nontemporal_load((const f4n*)p);
  return w.x * a.x + w.y * a.y + w.z * a.z + w.w * a.w;
}

// top-3 expert indices from logits (strict >, lower index wins ties — matches lax.top_k)
__device__ __forceinline__ void top3_from_logits(const float* l, int* ti) {
  int used0 = -1, used1 = -1;
  for (int kk = 0; kk < 3; ++kk) {
    float bv = -1e30f; int bi = -1;
#pragma unroll
    for (int e = 0; e < 8; ++e) {
      if (e == used0 || e == used1) continue;
      if (l[e] > bv) { bv = l[e]; bi = e; }
    }
    ti[kk] = bi;
    if (kk == 0) used0 = bi; else if (kk == 1) used1 = bi;
  }
}

// F1 (16 blocks): summ = mean_s feats + mod (float4); blocks 0-1: msum; block 0: zero logits
__global__ __launch_bounds__(256) void k_summ(const float* __restrict__ feats,
                                              const float* __restrict__ mod,
                                              float* __restrict__ summ,
                                              float* __restrict__ msum,
                                              float* __restrict__ logits) {
  int t4 = blockIdx.x * 256 + threadIdx.x;   // 0..4095 float4s
  int elem = t4 * 4;
  int m = elem >> 11;
  float4 s = make_float4(0.f, 0.f, 0.f, 0.f);
#pragma unroll
  for (int t = 0; t < 8; ++t)
    s = add4(s, *(const float4*)(feats + ((size_t)(m * 8 + t) << 11) + (elem & 2047)));
  float4 md = *(const float4*)(mod + elem);
  *(float4*)(summ + elem) = make_float4(s.x * 0.125f + md.x, s.y * 0.125f + md.y,
                                        s.z * 0.125f + md.z, s.w * 0.125f + md.w);
  if (t4 < 512) {   // msum over 2048 elems
    int i4 = t4 * 4;
    float4 acc = make_float4(0.f, 0.f, 0.f, 0.f);
#pragma unroll
    for (int mm = 0; mm < 8; ++mm)
      acc = add4(acc, *(const float4*)(mod + ((size_t)mm << 11) + i4));
    *(float4*)(msum + i4) = acc;
  }
  if (blockIdx.x == 0 && threadIdx.x < 8) logits[threadIdx.x] = 0.f;
}

// F2: blocks 0..511 -> h1 = relu([summ|ctx] @ rW1.T + rb1); 512..1023 -> q0 = x0 @ Wq.T + b
__global__ __launch_bounds__(256) void k_big1(const float* __restrict__ summ,
                                              const float* __restrict__ ctx,
                                              const float* __restrict__ feats,
                                              const float* __restrict__ mod,
                                              const float* __restrict__ rW1,
                                              const float* __restrict__ rb1,
                                              const float* __restrict__ W_in,
                                              const float* __restrict__ b_in,
                                              float* __restrict__ h1,
                                              float* __restrict__ q0) {
  __shared__ float As[8 * Dm];
  int tid = threadIdx.x, wave = tid >> 6, lane = tid & 63;
  if (blockIdx.x < 512) {
    for (int t = tid; t < 8 * Dm; t += 256) As[t] = summ[t];
    __syncthreads();
    int j = blockIdx.x * 4 + wave;
    const float* Wr = rW1 + (size_t)j * 4096;
    float acc[8] = {0, 0, 0, 0, 0, 0, 0, 0};
    float accC = 0.f;
    for (int i = lane * 4; i < Dm; i += 256) {
      float4 w1 = *(const float4*)(Wr + i);
      float4 w2 = *(const float4*)(Wr + 2048 + i);
      float4 c = *(const float4*)(ctx + i);
      accC += dot4(w2, c);
#pragma unroll
      for (int m = 0; m < 8; ++m) {
        float4 a = *(const float4*)(As + (m << 11) + i);
        acc[m] += dot4(w1, a);
      }
    }
#pragma unroll
    for (int o = 32; o > 0; o >>= 1) {
      accC += __shfl_down(accC, o, 64);
#pragma unroll
      for (int m = 0; m < 8; ++m) acc[m] += __shfl_down(acc[m], o, 64);
    }
    if (lane == 0) {
      float base = accC + rb1[j];
#pragma unroll
      for (int m = 0; m < 8; ++m) h1[(m << 11) + j] = fmaxf(acc[m] + base, 0.f);
    }
  } else {
    for (int t = tid; t < 8 * Dm; t += 256) {
      int m = t >> 11, col = t & 2047;
      As[t] = feats[(size_t)(m * 8) * Dm + col] + mod[(m << 11) + col];  // x[m,0,:]
    }
    __syncthreads();
    int j = (blockIdx.x - 512) * 4 + wave;
    const float* Wr = W_in + (size_t)j * Dm;
    float acc[8] = {0, 0, 0, 0, 0, 0, 0, 0};
    for (int i = lane * 4; i < Dm; i += 256) {
      float4 w = *(const float4*)(Wr + i);
#pragma unroll
      for (int m = 0; m < 8; ++m) {
        float4 a = *(const float4*)(As + (m << 11) + i);
        acc[m] += dot4(w, a);
      }
    }
#pragma unroll
    for (int o = 32; o > 0; o >>= 1)
#pragma unroll
      for (int m = 0; m < 8; ++m) acc[m] += __shfl_down(acc[m], o, 64);
    if (lane == 0) {
      float b = b_in[j];
#pragma unroll
      for (int m = 0; m < 8; ++m) q0[(m << 11) + j] = acc[m] + b;
    }
  }
}

// F3: blocks 0..255 -> h2 = relu(h1 @ rW2.T + rb2)
//     blocks 256..383 -> qw (per-head K projection, float4 weight loads, wave-split d)
__global__ __launch_bounds__(256) void k_big2(const float* __restrict__ h1,
                                              const float* __restrict__ rW2,
                                              const float* __restrict__ rb2,
                                              const float* __restrict__ q0,
                                              const float* __restrict__ W_in,
                                              float* __restrict__ h2,
                                              float* __restrict__ qw) {
  __shared__ float As[8 * Dm];
  int tid = threadIdx.x, wave = tid >> 6, lane = tid & 63;
  if (blockIdx.x < 256) {
    for (int t = tid; t < 8 * Dm; t += 256) As[t] = h1[t];
    __syncthreads();
    int j = blockIdx.x * 4 + wave;     // 0..1023
    const float* Wr = rW2 + (size_t)j * Dm;
    float acc[8] = {0, 0, 0, 0, 0, 0, 0, 0};
    for (int i = lane * 4; i < Dm; i += 256) {
      float4 w = *(const float4*)(Wr + i);
#pragma unroll
      for (int m = 0; m < 8; ++m) {
        float4 a = *(const float4*)(As + (m << 11) + i);
        acc[m] += dot4(w, a);
      }
    }
#pragma unroll
    for (int o = 32; o > 0; o >>= 1)
#pragma unroll
      for (int m = 0; m < 8; ++m) acc[m] += __shfl_down(acc[m], o, 64);
    if (lane == 0) {
      float b = rb2[j];
#pragma unroll
      for (int m = 0; m < 8; ++m) h2[m * 1024 + j] = fmaxf(acc[m] + b, 0.f);
    }
  } else {
    // qw phase: block covers (h, chunk of 256 cols); wave owns d-range of 32
    int bb = blockIdx.x - 256;          // 0..127
    int h = bb >> 3, chunk = bb & 7;
    int c0 = chunk * 256;
    float* qs = As;                     // [8][128]
    float* red = As + 1024;             // [4][8][256]
    for (int t = tid; t < 1024; t += 256) {
      int m = t >> 7, d = t & 127;
      qs[t] = q0[(m << 11) + h * 128 + d];
    }
    __syncthreads();
    float4 acc[8];
#pragma unroll
    for (int m = 0; m < 8; ++m) acc[m] = make_float4(0.f, 0.f, 0.f, 0.f);
    const float* Wb = W_in + (size_t)(Dm + h * 128 + wave * 32) * Dm + c0 + lane * 4;
#pragma unroll 8
    for (int d = 0; d < 32; ++d) {
      float4 wv = *(const float4*)(Wb + (size_t)d * Dm);
#pragma unroll
      for (int m = 0; m < 8; ++m) {
        float q = qs[(m << 7) + wave * 32 + d];
        acc[m].x += wv.x * q; acc[m].y += wv.y * q;
        acc[m].z += wv.z * q; acc[m].w += wv.w * q;
      }
    }
#pragma unroll
    for (int m = 0; m < 8; ++m)
      *(float4*)(red + (((wave << 3) + m) << 8) + lane * 4) = acc[m];
    __syncthreads();
    int m = tid >> 5, c = (tid & 31) * 8;
    float4 s0 = make_float4(0.f, 0.f, 0.f, 0.f);
    float4 s1 = make_float4(0.f, 0.f, 0.f, 0.f);
#pragma unroll
    for (int w = 0; w < 4; ++w) {
      s0 = add4(s0, *(const float4*)(red + (((w << 3) + m) << 8) + c));
      s1 = add4(s1, *(const float4*)(red + (((w << 3) + m) << 8) + c + 4));
    }
    float* dst = qw + (size_t)(m * 16 + h) * Dm + c0 + c;
    *(float4*)dst = s0;
    *(float4*)(dst + 4) = s1;
  }
}

// F4: 32 blocks x 256 thr (wave = one mh pair): redundant route + attw -> att[128][8]
__global__ __launch_bounds__(256) void k_attnw(const float* __restrict__ h2,
                                               const float* __restrict__ rW3,
                                               const float* __restrict__ rb3,
                                               const float* __restrict__ qw,
                                               const float* __restrict__ feats,
                                               float* __restrict__ att,
                                               float* __restrict__ out_rw) {
  __shared__ float sig[8], wm[64], sv[64], mask_s[8];
  int tid = threadIdx.x, wave = tid >> 6, lane = tid & 63;
  for (int mi = 0; mi < 2; ++mi) {
    int m = wave + mi * 4;
    float acc = 0.f;
    for (int i = lane * 4; i < 1024; i += 256) {
      float4 w = *(const float4*)(rW3 + i);
      float4 a = *(const float4*)(h2 + m * 1024 + i);
      acc += dot4(w, a);
    }
#pragma unroll
    for (int o = 32; o > 0; o >>= 1) acc += __shfl_down(acc, o, 64);
    if (lane == 0) sig[m] = 1.f / (1.f + expf(-(acc + rb3[0])));
  }
  __syncthreads();
  if (tid < 64) {
    float tot = 0.f;
#pragma unroll
    for (int m = 0; m < 8; ++m) tot += sig[m];
    int r = tid >> 3, cc = tid & 7;
    wm[tid] = (sig[r] / tot) * (sig[cc] / tot);
    if (blockIdx.x == 0 && tid < 8) out_rw[tid] = sig[tid] / tot;
  }
  __syncthreads();
  if (tid < 64) {
    float v = wm[tid];
    int rank = 0;
    for (int t = 0; t < 64; ++t) {
      float u = wm[t];
      rank += (u < v) || (u == v && t < tid);
    }
    sv[rank] = v;
  }
  __syncthreads();
  if (tid < 8) {
    double pos = 0.9 * 63.0;
    int lo = (int)pos;
    double frac = pos - (double)lo;
    float thr = (float)((double)sv[lo] + frac * ((double)sv[lo + 1] - (double)sv[lo]));
    mask_s[tid] = (wm[tid] < thr) ? -1e9f : 0.f;   // row 0 of wmat
  }
  __syncthreads();
  {
    int mh = blockIdx.x * 4 + wave;   // 0..127
    int m = mh >> 4;
    const float* qr = qw + (size_t)mh * Dm;
    float sc[8];
#pragma unroll
    for (int k = 0; k < 8; ++k) {
      const float* fr = feats + (size_t)(m * 8 + k) * Dm;
      float acc = 0.f;
#pragma unroll
      for (int i = 0; i < 8; ++i) {
        int idx = lane * 4 + i * 256;
        acc += dot4(*(const float4*)(qr + idx), *(const float4*)(fr + idx));
      }
#pragma unroll
      for (int o = 32; o > 0; o >>= 1) acc += __shfl_xor(acc, o, 64);
      sc[k] = acc * 0.08838834764831845f + mask_s[k];
    }
    float mx = sc[0];
#pragma unroll
    for (int k = 1; k < 8; ++k) mx = fmaxf(mx, sc[k]);
    float se = 0.f;
#pragma unroll
    for (int k = 0; k < 8; ++k) { sc[k] = expf(sc[k] - mx); se += sc[k]; }
    float inv = 1.f / se;
    if (lane == 0) {
#pragma unroll
      for (int k = 0; k < 8; ++k) att[mh * 8 + k] = sc[k] * inv;
    }
  }
}

// F5: grid (8,16): xbar[h][i-chunk] = (sum_b att*feats + msum)/8
__global__ __launch_bounds__(256) void k_xbar(const float* __restrict__ att,
                                              const float* __restrict__ feats,
                                              const float* __restrict__ msum,
                                              float* __restrict__ xbar) {
  __shared__ float aw[64];
  int h = blockIdx.y;
  int i = blockIdx.x * 256 + threadIdx.x;
  if (threadIdx.x < 64) {
    int m = threadIdx.x >> 3, k = threadIdx.x & 7;
    aw[threadIdx.x] = att[(m * 16 + h) * 8 + k];
  }
  __syncthreads();
  float acc = msum[i];
#pragma unroll
  for (int b = 0; b < 64; ++b) acc += aw[b] * feats[(size_t)b * Dm + i];
  xbar[(size_t)h * Dm + i] = acc * 0.125f;
}

// 8-rows-per-block matvec (2 rows/wave), activation direct from global (L1/L2-cached)
template <int ACT>
__global__ __launch_bounds__(256) void k_matvec8(const float* __restrict__ A, int G,
                                                 const float* __restrict__ W,
                                                 const float* __restrict__ b1,
                                                 float* __restrict__ out) {
  int j0 = blockIdx.x * 8;
  const float* Arow = A + (size_t)(j0 / G) * Dm;
  int wave = threadIdx.x >> 6, lane = threadIdx.x & 63;
  int j = j0 + wave * 2;
  const float* W0 = W + (size_t)j * Dm;
  const float* W1 = W0 + Dm;
  float acc0 = 0.f, acc1 = 0.f;
#pragma unroll 8
  for (int i = lane * 4; i < Dm; i += 256) {
    float4 a = *(const float4*)(Arow + i);
    acc0 += dot4(*(const float4*)(W0 + i), a);
    acc1 += dot4(*(const float4*)(W1 + i), a);
  }
#pragma unroll
  for (int o = 32; o > 0; o >>= 1) {
    acc0 += __shfl_down(acc0, o, 64);
    acc1 += __shfl_down(acc1, o, 64);
  }
  if (lane == 0) {
    float v0 = acc0 + b1[j], v1 = acc1 + b1[j + 1];
    if (ACT == 1) { v0 = fmaxf(v0, 0.f); v1 = fmaxf(v1, 0.f); }
    out[j] = v0;
    out[j + 1] = v1;
  }
}

// F8: 128 blocks: gbuf rows (in-register) + per-block partial gate logits via atomicAdd
__global__ __launch_bounds__(256) void k_gbufL(const float* __restrict__ attd,
                                               const float* __restrict__ gW1,
                                               const float* __restrict__ gb1,
                                               const float* __restrict__ gW2,
                                               float* __restrict__ logits) {
  __shared__ float gv[8];
  int tid = threadIdx.x, wave = tid >> 6, lane = tid & 63;
  int j0 = blockIdx.x * 8;
  int j = j0 + wave * 2;
  const float* W0 = gW1 + (size_t)j * Dm;
  const float* W1 = W0 + Dm;
  float acc0 = 0.f, acc1 = 0.f;
#pragma unroll 8
  for (int i = lane * 4; i < Dm; i += 256) {
    float4 a = *(const float4*)(attd + i);
    acc0 += dot4(*(const float4*)(W0 + i), a);
    acc1 += dot4(*(const float4*)(W1 + i), a);
  }
#pragma unroll
  for (int o = 32; o > 0; o >>= 1) {
    acc0 += __shfl_down(acc0, o, 64);
    acc1 += __shfl_down(acc1, o, 64);
  }
  if (lane == 0) {
    gv[wave * 2] = fmaxf(acc0 + gb1[j], 0.f);
    gv[wave * 2 + 1] = fmaxf(acc1 + gb1[j + 1], 0.f);
  }
  __syncthreads();
  if (tid < 8) {
    float pl = 0.f;
#pragma unroll
    for (int r = 0; r < 8; ++r) pl += gW2[tid * 1024 + j0 + r] * gv[r];
    atomicAdd(&logits[tid], pl);
  }
}

// expert matvec, 8 rows/block (2/wave); NON-TEMPORAL weight loads (single-use, spare L3)
template <int IN, int ACT>
__global__ __launch_bounds__(256) void k_expert8(const float* __restrict__ A,
                                                 int a_stride_kk,
                                                 const float* __restrict__ Wbase,
                                                 size_t wstride,
                                                 const float* __restrict__ bbase,
                                                 int bstride,
                                                 const float* __restrict__ logits,
                                                 const float* __restrict__ gb2,
                                                 float* __restrict__ out, int OUT) {
  int kk = blockIdx.y;
  float l[8];
#pragma unroll
  for (int e = 0; e < 8; ++e) l[e] = logits[e] + gb2[e];
  int ti[3];
  top3_from_logits(l, ti);
  int ei = ti[kk];
  const float* Arow = A + (size_t)kk * a_stride_kk;
  int wave = threadIdx.x >> 6, lane = threadIdx.x & 63;
  int j = blockIdx.x * 8 + wave * 2;
  const float* W0 = Wbase + (size_t)ei * wstride + (size_t)j * IN;
  const float* W1 = W0 + IN;
  float acc0 = 0.f, acc1 = 0.f;
#pragma unroll 8
  for (int i = lane * 4; i < IN; i += 256) {
    float4 a = *(const float4*)(Arow + i);
    acc0 += dot4nt(W0 + i, a);
    acc1 += dot4nt(W1 + i, a);
  }
#pragma unroll
  for (int o = 32; o > 0; o >>= 1) {
    acc0 += __shfl_down(acc0, o, 64);
    acc1 += __shfl_down(acc1, o, 64);
  }
  if (lane == 0) {
    const float* bb = bbase + (size_t)ei * bstride;
    float v0 = acc0 + bb[j], v1 = acc1 + bb[j + 1];
    if (ACT == 2) {
      v0 = 0.5f * v0 * (1.f + erff(v0 * 0.70710678118654752f));
      v1 = 0.5f * v1 * (1.f + erff(v1 * 0.70710678118654752f));
    }
    out[(size_t)kk * OUT + j] = v0;
    out[(size_t)kk * OUT + j + 1] = v1;
  }
}

// F11: per-expert LayerNorm + gated combine (gate recomputed in-register from logits)
__global__ __launch_bounds__(256) void k_final(const float* __restrict__ y,
                                               const float* __restrict__ logits,
                                               const float* __restrict__ gb2,
                                               const float* __restrict__ e_gamma,
                                               const float* __restrict__ e_beta,
                                               float* __restrict__ outp) {
  __shared__ float ws_s[4], ws_ss[4];
  int tid = threadIdx.x, wave = tid >> 6, lane = tid & 63;
  float l[8];
#pragma unroll
  for (int e = 0; e < 8; ++e) l[e] = logits[e] + gb2[e];
  int ti[3];
  top3_from_logits(l, ti);
  float mx = l[0];
#pragma unroll
  for (int e = 1; e < 8; ++e) mx = fmaxf(mx, l[e]);
  float se = 0.f;
  float p[8];
#pragma unroll
  for (int e = 0; e < 8; ++e) { p[e] = expf(l[e] - mx); se += p[e]; }
  float tv0 = p[ti[0]] / se, tv1 = p[ti[1]] / se, tv2 = p[ti[2]] / se;
  float g0 = 1.f, g1 = expf(tv1 - tv0), g2 = expf(tv2 - tv0);
  float gs = g0 + g1 + g2;
  float gates[3] = {g0 / gs, g1 / gs, g2 / gs};
  float fused[8];
#pragma unroll
  for (int t = 0; t < 8; ++t) fused[t] = 0.f;
  for (int kk = 0; kk < 3; ++kk) {
    int ei = ti[kk];
    float gk = gates[kk];
    const float* yr = y + (size_t)kk * Dm;
    float s = 0.f, ss = 0.f;
    float vbuf[8];
#pragma unroll
    for (int t = 0; t < 8; ++t) {
      float v = yr[tid + 256 * t];
      vbuf[t] = v;
      s += v; ss += v * v;
    }
#pragma unroll
    for (int o = 32; o > 0; o >>= 1) {
      s += __shfl_down(s, o, 64);
      ss += __shfl_down(ss, o, 64);
    }
    if (lane == 0) { ws_s[wave] = s; ws_ss[wave] = ss; }
    __syncthreads();
    float S = ws_s[0] + ws_s[1] + ws_s[2] + ws_s[3];
    float SS = ws_ss[0] + ws_ss[1] + ws_ss[2] + ws_ss[3];
    float mu = S * (1.f / 2048.f);
    float var = SS * (1.f / 2048.f) - mu * mu;
    float rstd = rsqrtf(var + 1e-5f);
#pragma unroll
    for (int t = 0; t < 8; ++t) {
      int d = tid + 256 * t;
      fused[t] += gk * ((vbuf[t] - mu) * rstd * e_gamma[(size_t)ei * Dm + d] +
                        e_beta[(size_t)ei * Dm + d]);
    }
    __syncthreads();
  }
#pragma unroll
  for (int t = 0; t < 8; ++t) outp[tid + 256 * t] = fused[t];
}

}  // namespace

extern "C" void kernel_launch(void* const* d_in, const int* in_sizes, int n_in,
                              void* d_out, int out_size, void* d_ws, size_t ws_size,
                              hipStream_t stream) {
  const float* feats   = (const float*)d_in[0];
  const float* context = (const float*)d_in[1];
  const float* mod_emb = (const float*)d_in[2];
  const float* rW1 = (const float*)d_in[3];
  const float* rb1 = (const float*)d_in[4];
  const float* rW2 = (const float*)d_in[5];
  const float* rb2 = (const float*)d_in[6];
  const float* rW3 = (const float*)d_in[7];
  const float* rb3 = (const float*)d_in[8];
  const float* W_in  = (const float*)d_in[9];
  const float* b_in  = (const float*)d_in[10];
  const float* W_out = (const float*)d_in[11];
  const float* b_out = (const float*)d_in[12];
  const float* gW1 = (const float*)d_in[13];
  const float* gb1 = (const float*)d_in[14];
  const float* gW2 = (const float*)d_in[15];
  const float* gb2 = (const float*)d_in[16];
  const float* eW1 = (const float*)d_in[17];
  const float* eb1 = (const float*)d_in[18];
  const float* eW2 = (const float*)d_in[19];
  const float* eb2 = (const float*)d_in[20];
  const float* e_gamma = (const float*)d_in[21];
  const float* e_beta  = (const float*)d_in[22];
  float* out = (float*)d_out;
  float* ws = (float*)d_ws;

  float* summ   = ws;                  // 16384
  float* msum   = summ + 16384;        // 2048
  float* h1     = msum + 2048;         // 16384
  float* h2     = h1 + 16384;          // 8192
  float* q0     = h2 + 8192;           // 16384
  float* qw     = q0 + 16384;          // 262144
  float* att    = qw + 262144;         // 1024
  float* xbar   = att + 1024;          // 32768
  float* obar   = xbar + 32768;        // 2048
  float* attd   = obar + 2048;         // 2048
  float* logits = attd + 2048;         // 8
  float* hh     = logits + 8;          // 12288
  float* ybuf   = hh + 12288;          // 6144

  const int BIG = 1 << 30;

  hipLaunchKernelGGL(k_summ, dim3(16), dim3(256), 0, stream,
                     feats, mod_emb, summ, msum, logits);
  hipLaunchKernelGGL(k_big1, dim3(1024), dim3(256), 0, stream,
                     summ, context, feats, mod_emb, rW1, rb1, W_in, b_in, h1, q0);
  hipLaunchKernelGGL(k_big2, dim3(384), dim3(256), 0, stream,
                     h1, rW2, rb2, q0, W_in, h2, qw);
  hipLaunchKernelGGL(k_attnw, dim3(32), dim3(256), 0, stream,
                     h2, rW3, rb3, qw, feats, att, out + 2048);
  hipLaunchKernelGGL(k_xbar, dim3(8, 16), dim3(256), 0, stream, att, feats, msum, xbar);
  hipLaunchKernelGGL(k_matvec8<0>, dim3(256), dim3(256), 0, stream,
                     xbar, 128, W_in + (size_t)4096 * 2048, b_in + 4096, obar);
  hipLaunchKernelGGL(k_matvec8<0>, dim3(256), dim3(256), 0, stream,
                     obar, BIG, W_out, b_out, attd);
  hipLaunchKernelGGL(k_gbufL, dim3(128), dim3(256), 0, stream,
                     attd, gW1, gb1, gW2, logits);
  hipLaunchKernelGGL((k_expert8<2048, 2>), dim3(512, 3), dim3(256), 0, stream,
                     attd, 0, eW1, (size_t)4096 * 2048, eb1, 4096, logits, gb2, hh, 4096);
  hipLaunchKernelGGL((k_expert8<4096, 0>), dim3(256, 3), dim3(256), 0, stream,
                     hh, 4096, eW2, (size_t)2048 * 4096, eb2, 2048, logits, gb2, ybuf, 2048);
  hipLaunchKernelGGL(k_final, dim3(1), dim3(256), 0, stream,
                     ybuf, logits, gb2, e_gamma, e_beta, out);
}